// Round 1
// baseline (321.857 us; speedup 1.0000x reference)
//
#include <hip/hip_runtime.h>

typedef unsigned short ushort_t;
typedef __bf16 bf16x8 __attribute__((ext_vector_type(8)));
typedef float f32x4 __attribute__((ext_vector_type(4)));

__device__ __forceinline__ ushort_t f2bf(float f) {
    unsigned u = __builtin_bit_cast(unsigned, f);
    unsigned r = (u + 0x7fffu + ((u >> 16) & 1u)) >> 16;
    return (ushort_t)r;
}

__device__ __forceinline__ void async16(const ushort_t* g, void* lds) {
    __builtin_amdgcn_global_load_lds(
        (const __attribute__((address_space(1))) void*)g,
        (__attribute__((address_space(3))) void*)lds, 16, 0, 0);
}

// ---------------- prep kernels ----------------

__global__ void k_conv_x4(const float4* __restrict__ in, ushort4* __restrict__ out, int n4) {
    int i = blockIdx.x * blockDim.x + threadIdx.x;
    int st = gridDim.x * blockDim.x;
    for (; i < n4; i += st) {
        float4 f = in[i];
        ushort4 o;
        o.x = f2bf(f.x); o.y = f2bf(f.y); o.z = f2bf(f.z); o.w = f2bf(f.w);
        out[i] = o;
    }
}

__global__ void k_conv_f32_bf16(const float* __restrict__ in, ushort_t* __restrict__ out, int n) {
    int i = blockIdx.x * blockDim.x + threadIdx.x;
    int st = gridDim.x * blockDim.x;
    for (; i < n; i += st) out[i] = f2bf(in[i]);
}

__global__ void k_prep_wcat(const float* __restrict__ wu, const float* __restrict__ wv,
                            ushort_t* __restrict__ wcat, int n) {
    int i = blockIdx.x * blockDim.x + threadIdx.x;
    int st = gridDim.x * blockDim.x;
    for (; i < n; i += st)
        wcat[i] = f2bf(i < 1048576 ? wu[i] : wv[i - 1048576]);
}

__global__ void k_prep_bias1(const float* __restrict__ wvb, float* __restrict__ bias1) {
    int i = blockIdx.x * blockDim.x + threadIdx.x;
    if (i < 2048) bias1[i] = (i < 1024) ? 0.0f : wvb[i - 1024];
}

__global__ void k_prep_helperT(const float* __restrict__ hw, ushort_t* __restrict__ hT) {
    int i = blockIdx.x * blockDim.x + threadIdx.x;
    if (i < 65536) {
        int c = i >> 6, d = i & 63;
        hT[i] = f2bf(hw[d * 1024 + c]);   // helperT[c][d] = helper_w[d][c]
    }
}

// ---------------- main GEMM: C[m,n] = sum_k A[m,k] * Bt[n,k] (+bias[n]) ----------------
// 128x128 tile, BK=32, 4 waves, each wave a 64x64 quadrant (4x4 frags of 16x16x32 bf16).

template<int OUT_F32>
__global__ __launch_bounds__(256)
void k_gemm_bt(const ushort_t* __restrict__ A, const ushort_t* __restrict__ Bt,
               void* __restrict__ Cv, const float* __restrict__ bias,
               int K, int ldA, int ldB, int ldC,
               long sA, long sB, long sC)
{
    __shared__ ushort_t As[128 * 32];
    __shared__ ushort_t Bs[128 * 32];
    const int z = blockIdx.z;
    const ushort_t* Ab = A + (long)z * sA;
    const ushort_t* Bb = Bt + (long)z * sB;
    const int m0 = blockIdx.x * 128;
    const int n0 = blockIdx.y * 128;
    const int tid = threadIdx.x;
    const int w = tid >> 6;
    const int lane = tid & 63;
    const int l15 = lane & 15, l4 = lane >> 4;
    const int wr = (w >> 1) * 64, wc = (w & 1) * 64;

    f32x4 acc[4][4] = {};

    const int srow = lane >> 2;          // 0..15 within a 16-row segment
    const int skcol = (lane & 3) << 3;   // 0,8,16,24

    for (int kt = 0; kt < K; kt += 32) {
        __syncthreads();
        #pragma unroll
        for (int q = 0; q < 2; ++q) {
            const int seg = q * 4 + w;                 // 0..7, wave-uniform
            const int r = seg * 16 + srow;             // 0..127
            async16(Ab + (long)(m0 + r) * ldA + kt + skcol, (char*)As + seg * 1024);
            async16(Bb + (long)(n0 + r) * ldB + kt + skcol, (char*)Bs + seg * 1024);
        }
        __syncthreads();
        bf16x8 af[4], bfr[4];
        #pragma unroll
        for (int i = 0; i < 4; ++i) {
            af[i]  = *(const bf16x8*)&As[(wr + i * 16 + l15) * 32 + l4 * 8];
            bfr[i] = *(const bf16x8*)&Bs[(wc + i * 16 + l15) * 32 + l4 * 8];
        }
        #pragma unroll
        for (int i = 0; i < 4; ++i)
            #pragma unroll
            for (int j = 0; j < 4; ++j)
                acc[i][j] = __builtin_amdgcn_mfma_f32_16x16x32_bf16(af[i], bfr[j], acc[i][j], 0, 0, 0);
    }

    #pragma unroll
    for (int i = 0; i < 4; ++i) {
        #pragma unroll
        for (int j = 0; j < 4; ++j) {
            const int row0 = m0 + wr + i * 16 + l4 * 4;
            const int col  = n0 + wc + j * 16 + l15;
            const float bv = bias ? bias[col] : 0.0f;
            #pragma unroll
            for (int e = 0; e < 4; ++e) {
                float v = acc[i][j][e] + bv;
                if (OUT_F32)
                    ((float*)Cv)[(long)z * sC + (long)(row0 + e) * ldC + col] = v;
                else
                    ((ushort_t*)Cv)[(long)z * sC + (long)(row0 + e) * ldC + col] = f2bf(v);
            }
        }
    }
}

// ---------------- attention kernel: one block per (h, b) ----------------
// S = Uh^T Vh / 32 (64x64, K=2048) -> causal softmax -> attT[b][c2][h*64+s] = (P @ helper)[s][c2]

__global__ __launch_bounds__(256)
void k_attn(const ushort_t* __restrict__ uv, const ushort_t* __restrict__ helperT,
            ushort_t* __restrict__ attT)
{
    __shared__ ushort_t UT[64 * 40];   // UT[s][t_local], padded rows (80B, 16B-aligned)
    __shared__ ushort_t VT[64 * 40];
    __shared__ ushort_t PA[64 * 72];   // P bf16, padded rows (144B, 16B-aligned)
    const int h = blockIdx.x, b = blockIdx.y;
    const int tid = threadIdx.x;
    const int w = tid >> 6, lane = tid & 63;
    const int l15 = lane & 15, l4 = lane >> 4;

    f32x4 sf[4] = {};   // wave w owns rows s in [w*16, w*16+16), all 64 cols
    const long base = ((long)b * 2048) * 2048 + h * 64;

    for (int kt = 0; kt < 2048; kt += 32) {
        __syncthreads();
        #pragma unroll
        for (int q = 0; q < 2; ++q) {
            int id = q * 256 + tid;            // 0..511
            int tl = id >> 4;                  // 0..31
            int sg = (id & 15) << 2;           // 0,4,...,60
            const ushort_t* g = uv + base + (long)(kt + tl) * 2048 + sg;
            ushort4 uu = *(const ushort4*)g;
            ushort4 vv = *(const ushort4*)(g + 1024);
            UT[(sg + 0) * 40 + tl] = uu.x; UT[(sg + 1) * 40 + tl] = uu.y;
            UT[(sg + 2) * 40 + tl] = uu.z; UT[(sg + 3) * 40 + tl] = uu.w;
            VT[(sg + 0) * 40 + tl] = vv.x; VT[(sg + 1) * 40 + tl] = vv.y;
            VT[(sg + 2) * 40 + tl] = vv.z; VT[(sg + 3) * 40 + tl] = vv.w;
        }
        __syncthreads();
        bf16x8 a = *(const bf16x8*)&UT[(w * 16 + l15) * 40 + l4 * 8];
        #pragma unroll
        for (int nf = 0; nf < 4; ++nf) {
            bf16x8 bb = *(const bf16x8*)&VT[(nf * 16 + l15) * 40 + l4 * 8];
            sf[nf] = __builtin_amdgcn_mfma_f32_16x16x32_bf16(a, bb, sf[nf], 0, 0, 0);
        }
    }

    // softmax over the 64 cols of each row; row s lives on 16 lanes (same l4), 4 regs
    const float scale = 0.03125f;   // 1/sqrt(1024)
    const int rb = w * 16 + l4 * 4;
    #pragma unroll
    for (int j = 0; j < 4; ++j) {
        const int srowi = rb + j;
        float v[4];
        #pragma unroll
        for (int nf = 0; nf < 4; ++nf) {
            int col = nf * 16 + l15;
            v[nf] = (col <= srowi) ? sf[nf][j] * scale : -3.0e38f;
        }
        float mx = fmaxf(fmaxf(v[0], v[1]), fmaxf(v[2], v[3]));
        #pragma unroll
        for (int o = 1; o < 16; o <<= 1) mx = fmaxf(mx, __shfl_xor(mx, o, 64));
        float s = 0.0f;
        #pragma unroll
        for (int nf = 0; nf < 4; ++nf) { v[nf] = __expf(v[nf] - mx); s += v[nf]; }
        #pragma unroll
        for (int o = 1; o < 16; o <<= 1) s += __shfl_xor(s, o, 64);
        const float inv = 1.0f / s;
        #pragma unroll
        for (int nf = 0; nf < 4; ++nf)
            PA[srowi * 72 + nf * 16 + l15] = f2bf(v[nf] * inv);
    }
    __syncthreads();

    // att2 = P @ helper : A-frags from PA (all 64 rows), each wave covers 256 output cols
    bf16x8 af[4][2];
    #pragma unroll
    for (int mf = 0; mf < 4; ++mf)
        #pragma unroll
        for (int kk = 0; kk < 2; ++kk)
            af[mf][kk] = *(const bf16x8*)&PA[(mf * 16 + l15) * 72 + kk * 32 + l4 * 8];

    const int nbase = w * 256;
    for (int nb = 0; nb < 4; ++nb) {
        const int n0 = nbase + nb * 64;
        f32x4 acc[4][4] = {};
        #pragma unroll
        for (int kk = 0; kk < 2; ++kk) {
            #pragma unroll
            for (int nf = 0; nf < 4; ++nf) {
                bf16x8 bb = *(const bf16x8*)&helperT[(n0 + nf * 16 + l15) * 64 + kk * 32 + l4 * 8];
                #pragma unroll
                for (int mf = 0; mf < 4; ++mf)
                    acc[mf][nf] = __builtin_amdgcn_mfma_f32_16x16x32_bf16(af[mf][kk], bb, acc[mf][nf], 0, 0, 0);
            }
        }
        #pragma unroll
        for (int mf = 0; mf < 4; ++mf) {
            #pragma unroll
            for (int nf = 0; nf < 4; ++nf) {
                int c2 = n0 + nf * 16 + l15;
                int s0 = mf * 16 + l4 * 4;
                ushort4 st;
                st.x = f2bf(acc[mf][nf][0]); st.y = f2bf(acc[mf][nf][1]);
                st.z = f2bf(acc[mf][nf][2]); st.w = f2bf(acc[mf][nf][3]);
                *(ushort4*)&attT[((long)b * 1024 + c2) * 1024 + h * 64 + s0] = st;
            }
        }
    }
}

// ---------------- launch ----------------

extern "C" void kernel_launch(void* const* d_in, const int* in_sizes, int n_in,
                              void* d_out, int out_size, void* d_ws, size_t ws_size,
                              hipStream_t stream)
{
    (void)in_sizes; (void)n_in; (void)out_size; (void)ws_size;
    const float* x   = (const float*)d_in[0];
    const float* wu  = (const float*)d_in[1];
    const float* wv  = (const float*)d_in[2];
    const float* wvb = (const float*)d_in[3];
    const float* hw  = (const float*)d_in[4];
    const float* cpw = (const float*)d_in[5];
    const float* cpb = (const float*)d_in[6];
    float* out = (float*)d_out;

    char* ws = (char*)d_ws;
    // layout (bytes):
    ushort_t* x_bf    = (ushort_t*)(ws);                               // 32 MB  [B*T, C]
    ushort_t* uv      = (ushort_t*)(ws + 33554432L);                   // 64 MB  [B*T, 2C]
    ushort_t* yT      = uv;                                            // 32 MB, reuses uv after K2
    ushort_t* attT    = (ushort_t*)(ws + 33554432L + 67108864L);       // 16 MB  [B, 1024, 1024]
    ushort_t* wcat    = (ushort_t*)(ws + 33554432L + 67108864L + 16777216L);         // 4 MB
    ushort_t* helperT = (ushort_t*)(ws + 33554432L + 67108864L + 16777216L + 4194304L); // 128 KB
    ushort_t* cproj   = (ushort_t*)(ws + 33554432L + 67108864L + 16777216L + 4194304L + 131072L); // 2 MB
    float*    bias1   = (float*)   (ws + 33554432L + 67108864L + 16777216L + 4194304L + 131072L + 2097152L); // 8 KB

    // prep
    k_conv_x4     <<<2048, 256, 0, stream>>>((const float4*)x, (ushort4*)x_bf, 4194304);
    k_prep_wcat   <<<2048, 256, 0, stream>>>(wu, wv, wcat, 2097152);
    k_prep_bias1  <<<8, 256, 0, stream>>>(wvb, bias1);
    k_prep_helperT<<<256, 256, 0, stream>>>(hw, helperT);
    k_conv_f32_bf16<<<2048, 256, 0, stream>>>(cpw, cproj, 1048576);

    // K1: uv = x @ [w_u; w_v]^T + [0; b_v]   (M=16384, N=2048, K=1024)
    {
        dim3 g(128, 16, 1);
        k_gemm_bt<0><<<g, 256, 0, stream>>>(x_bf, wcat, uv, bias1,
                                            1024, 1024, 1024, 2048, 0, 0, 0);
    }
    // K2: per (h,b) attention -> attT
    {
        dim3 g(16, 8, 1);
        k_attn<<<g, 256, 0, stream>>>(uv, helperT, attT);
    }
    // K3: yT[b] = attT[b] @ x[b]^T   (M=1024, N=2048, K=1024, batched over b)
    {
        dim3 g(8, 16, 8);
        k_gemm_bt<0><<<g, 256, 0, stream>>>(attT, x_bf, yT, nullptr,
                                            1024, 1024, 1024, 2048,
                                            1048576L, 2097152L, 2097152L);
    }
    // K4: out = Z @ c_proj^T + b   (Z = yT flat [16384,1024], fp32 out)
    {
        dim3 g(128, 8, 1);
        k_gemm_bt<1><<<g, 256, 0, stream>>>(yT, cproj, (void*)out, cpb,
                                            1024, 1024, 1024, 1024, 0, 0, 0);
    }
}

// Round 2
// 268.309 us; speedup vs baseline: 1.1996x; 1.1996x over previous
//
#include <hip/hip_runtime.h>

typedef unsigned short ushort_t;
typedef __bf16 bf16x8 __attribute__((ext_vector_type(8)));
typedef float f32x4 __attribute__((ext_vector_type(4)));

__device__ __forceinline__ ushort_t f2bf(float f) {
    unsigned u = __builtin_bit_cast(unsigned, f);
    unsigned r = (u + 0x7fffu + ((u >> 16) & 1u)) >> 16;
    return (ushort_t)r;
}

__device__ __forceinline__ void async16(const ushort_t* g, void* lds) {
    __builtin_amdgcn_global_load_lds(
        (const __attribute__((address_space(1))) void*)g,
        (__attribute__((address_space(3))) void*)lds, 16, 0, 0);
}

// ---------------- prep kernels ----------------

__global__ void k_conv_x4(const float4* __restrict__ in, ushort4* __restrict__ out, int n4) {
    int i = blockIdx.x * blockDim.x + threadIdx.x;
    int st = gridDim.x * blockDim.x;
    for (; i < n4; i += st) {
        float4 f = in[i];
        ushort4 o;
        o.x = f2bf(f.x); o.y = f2bf(f.y); o.z = f2bf(f.z); o.w = f2bf(f.w);
        out[i] = o;
    }
}

__global__ void k_conv_f32_bf16(const float* __restrict__ in, ushort_t* __restrict__ out, int n) {
    int i = blockIdx.x * blockDim.x + threadIdx.x;
    int st = gridDim.x * blockDim.x;
    for (; i < n; i += st) out[i] = f2bf(in[i]);
}

__global__ void k_prep_wcat(const float* __restrict__ wu, const float* __restrict__ wv,
                            ushort_t* __restrict__ wcat, int n) {
    int i = blockIdx.x * blockDim.x + threadIdx.x;
    int st = gridDim.x * blockDim.x;
    for (; i < n; i += st)
        wcat[i] = f2bf(i < 1048576 ? wu[i] : wv[i - 1048576]);
}

__global__ void k_prep_bias1(const float* __restrict__ wvb, float* __restrict__ bias1) {
    int i = blockIdx.x * blockDim.x + threadIdx.x;
    if (i < 2048) bias1[i] = (i < 1024) ? 0.0f : wvb[i - 1024];
}

__global__ void k_prep_helperT(const float* __restrict__ hw, ushort_t* __restrict__ hT) {
    int i = blockIdx.x * blockDim.x + threadIdx.x;
    if (i < 65536) {
        int c = i >> 6, d = i & 63;
        hT[i] = f2bf(hw[d * 1024 + c]);   // helperT[c][d] = helper_w[d][c]
    }
}

// ---------------- main GEMM: C[m,n] = sum_k A[m,k] * Bt[n,k] (+bias[n]) ----------------
// 128x128 tile, BK=64, XOR-swizzled LDS (conflict-free), 4 waves, 64x64 quadrant each.
// OUT_MODE: 0 = bf16 row-major, 1 = f32 row-major, 2 = bf16 transposed (writes C^T[n][m], ldC = C^T row len)

template<int OUT_MODE>
__global__ __launch_bounds__(256)
void k_gemm_bt(const ushort_t* __restrict__ A, const ushort_t* __restrict__ Bt,
               void* __restrict__ Cv, const float* __restrict__ bias,
               int K, int ldA, int ldB, int ldC,
               long sA, long sB, long sC)
{
    __shared__ ushort_t smem[16896];     // staging: As=smem[0:8192], Bs=smem[8192:16384]; epilogue: 128x132 transpose
    ushort_t* As = smem;                 // [128 rows][64 k] bf16, 128B rows, chunk-swizzled
    ushort_t* Bs = smem + 8192;
    const int z = blockIdx.z;
    const ushort_t* Ab = A + (long)z * sA;
    const ushort_t* Bb = Bt + (long)z * sB;
    const int m0 = blockIdx.x * 128;
    const int n0 = blockIdx.y * 128;
    const int tid = threadIdx.x;
    const int w = tid >> 6;
    const int lane = tid & 63;
    const int l15 = lane & 15, l4 = lane >> 4;
    const int wr = (w >> 1) * 64, wc = (w & 1) * 64;

    f32x4 acc[4][4] = {};

    // staging: linear LDS dest (base + lane*16); row = seg*8 + (lane>>3), phys chunk = lane&7
    // phys chunk p holds global chunk p ^ (row&7)  (involution)
    const int srow = lane >> 3;                  // 0..7
    const int gchunk = (lane & 7) ^ srow;        // pre-swizzled global 16B-chunk index

    for (int kt = 0; kt < K; kt += 64) {
        __syncthreads();
        #pragma unroll
        for (int q = 0; q < 4; ++q) {
            const int seg = w * 4 + q;           // 0..15, wave-uniform
            const int r = seg * 8 + srow;        // 0..127
            async16(Ab + (long)(m0 + r) * ldA + kt + gchunk * 8, (char*)As + seg * 1024);
            async16(Bb + (long)(n0 + r) * ldB + kt + gchunk * 8, (char*)Bs + seg * 1024);
        }
        __syncthreads();
        #pragma unroll
        for (int kk = 0; kk < 2; ++kk) {
            bf16x8 af[4], bfr[4];
            const int swz = ((kk * 4 + l4) ^ (l15 & 7)) * 8;   // swizzled element offset within row
            #pragma unroll
            for (int i = 0; i < 4; ++i) {
                af[i]  = *(const bf16x8*)&As[(wr + i * 16 + l15) * 64 + swz];
                bfr[i] = *(const bf16x8*)&Bs[(wc + i * 16 + l15) * 64 + swz];
            }
            #pragma unroll
            for (int i = 0; i < 4; ++i)
                #pragma unroll
                for (int j = 0; j < 4; ++j)
                    acc[i][j] = __builtin_amdgcn_mfma_f32_16x16x32_bf16(af[i], bfr[j], acc[i][j], 0, 0, 0);
        }
    }

    if (OUT_MODE == 2) {
        // transpose epilogue: stage C tile (bf16, +bias) into smem [128 m][132 pad], write C^T coalesced
        __syncthreads();
        #pragma unroll
        for (int i = 0; i < 4; ++i) {
            #pragma unroll
            for (int j = 0; j < 4; ++j) {
                const int n = wc + j * 16 + l15;
                const float bv = bias ? bias[n0 + n] : 0.0f;
                #pragma unroll
                for (int e = 0; e < 4; ++e) {
                    const int m = wr + i * 16 + l4 * 4 + e;
                    smem[m * 132 + n] = f2bf(acc[i][j][e] + bv);
                }
            }
        }
        __syncthreads();
        const int nr = tid & 127;      // C^T row (= n)
        const int mh = tid >> 7;       // m half
        ushort_t* Ct = (ushort_t*)Cv;
        #pragma unroll
        for (int v = 0; v < 8; ++v) {
            uint4 pk;
            unsigned* pw = (unsigned*)&pk;
            #pragma unroll
            for (int p2 = 0; p2 < 4; ++p2) {
                const int m = mh * 64 + v * 8 + p2 * 2;
                unsigned lo = smem[m * 132 + nr];
                unsigned hi = smem[(m + 1) * 132 + nr];
                pw[p2] = lo | (hi << 16);
            }
            *(uint4*)&Ct[(long)(n0 + nr) * ldC + m0 + mh * 64 + v * 8] = pk;
        }
    } else {
        #pragma unroll
        for (int i = 0; i < 4; ++i) {
            #pragma unroll
            for (int j = 0; j < 4; ++j) {
                const int row0 = m0 + wr + i * 16 + l4 * 4;
                const int col  = n0 + wc + j * 16 + l15;
                const float bv = bias ? bias[col] : 0.0f;
                #pragma unroll
                for (int e = 0; e < 4; ++e) {
                    float vv = acc[i][j][e] + bv;
                    if (OUT_MODE == 1)
                        ((float*)Cv)[(long)z * sC + (long)(row0 + e) * ldC + col] = vv;
                    else
                        ((ushort_t*)Cv)[(long)z * sC + (long)(row0 + e) * ldC + col] = f2bf(vv);
                }
            }
        }
    }
}

// ---------------- attention part 1: partial S from uvT (no LDS) ----------------
// block (h, b, kq): S_partial[s][s'] = sum_{t in kq half} u[s][t] * v[t][s']
// A-frag rows = uvT[h*64+s], B-frag rows = uvT[1024+h*64+s']; both contiguous along t.

__global__ __launch_bounds__(256)
void k_attn_s(const ushort_t* __restrict__ uvT, float* __restrict__ Sp)
{
    const int h = blockIdx.x, b = blockIdx.y, kq = blockIdx.z;
    const int tid = threadIdx.x;
    const int w = tid >> 6, lane = tid & 63;
    const int l15 = lane & 15, l4 = lane >> 4;

    f32x4 sf[4] = {};
    const long tbase = (long)b * 2048 + kq * 1024 + l4 * 8;
    const ushort_t* pa  = uvT + (long)(h * 64 + w * 16 + l15) * 16384 + tbase;
    const ushort_t* pb0 = uvT + (long)(1024 + h * 64 + l15) * 16384 + tbase;

    #pragma unroll 2
    for (int kt = 0; kt < 1024; kt += 32) {
        bf16x8 a = *(const bf16x8*)(pa + kt);
        #pragma unroll
        for (int nf = 0; nf < 4; ++nf) {
            bf16x8 bb = *(const bf16x8*)(pb0 + (long)(nf * 16) * 16384 + kt);
            sf[nf] = __builtin_amdgcn_mfma_f32_16x16x32_bf16(a, bb, sf[nf], 0, 0, 0);
        }
    }

    float* outp = Sp + (long)((kq * 8 + b) * 16 + h) * 4096;
    #pragma unroll
    for (int nf = 0; nf < 4; ++nf)
        #pragma unroll
        for (int j = 0; j < 4; ++j)
            outp[(w * 16 + l4 * 4 + j) * 64 + nf * 16 + l15] = sf[nf][j];
}

// ---------------- attention part 2: sum partials, softmax, P @ helper -> attT ----------------

__global__ __launch_bounds__(256)
void k_attn_f(const float* __restrict__ Sp, const ushort_t* __restrict__ helperT,
              ushort_t* __restrict__ attT)
{
    __shared__ ushort_t PA[64 * 72];
    const int h = blockIdx.x, b = blockIdx.y;
    const int tid = threadIdx.x;
    const int w = tid >> 6, lane = tid & 63;
    const int l15 = lane & 15, l4 = lane >> 4;

    const float* s0 = Sp + (long)((0 * 8 + b) * 16 + h) * 4096;
    const float* s1 = Sp + (long)((1 * 8 + b) * 16 + h) * 4096;

    const float scale = 0.03125f;   // 1/sqrt(1024)
    const int rb = w * 16 + l4 * 4;
    #pragma unroll
    for (int j = 0; j < 4; ++j) {
        const int srowi = rb + j;
        float v[4];
        #pragma unroll
        for (int nf = 0; nf < 4; ++nf) {
            const int col = nf * 16 + l15;
            const int idx = srowi * 64 + col;
            const float sv = s0[idx] + s1[idx];
            v[nf] = (col <= srowi) ? sv * scale : -3.0e38f;
        }
        float mx = fmaxf(fmaxf(v[0], v[1]), fmaxf(v[2], v[3]));
        #pragma unroll
        for (int o = 1; o < 16; o <<= 1) mx = fmaxf(mx, __shfl_xor(mx, o, 64));
        float s = 0.0f;
        #pragma unroll
        for (int nf = 0; nf < 4; ++nf) { v[nf] = __expf(v[nf] - mx); s += v[nf]; }
        #pragma unroll
        for (int o = 1; o < 16; o <<= 1) s += __shfl_xor(s, o, 64);
        const float inv = 1.0f / s;
        #pragma unroll
        for (int nf = 0; nf < 4; ++nf)
            PA[srowi * 72 + nf * 16 + l15] = f2bf(v[nf] * inv);
    }
    __syncthreads();

    bf16x8 af[4][2];
    #pragma unroll
    for (int mf = 0; mf < 4; ++mf)
        #pragma unroll
        for (int kk = 0; kk < 2; ++kk)
            af[mf][kk] = *(const bf16x8*)&PA[(mf * 16 + l15) * 72 + kk * 32 + l4 * 8];

    const int nbase = w * 256;
    for (int nb = 0; nb < 4; ++nb) {
        const int n0 = nbase + nb * 64;
        f32x4 acc[4][4] = {};
        #pragma unroll
        for (int kk = 0; kk < 2; ++kk) {
            #pragma unroll
            for (int nf = 0; nf < 4; ++nf) {
                bf16x8 bb = *(const bf16x8*)&helperT[(n0 + nf * 16 + l15) * 64 + kk * 32 + l4 * 8];
                #pragma unroll
                for (int mf = 0; mf < 4; ++mf)
                    acc[mf][nf] = __builtin_amdgcn_mfma_f32_16x16x32_bf16(af[mf][kk], bb, acc[mf][nf], 0, 0, 0);
            }
        }
        #pragma unroll
        for (int mf = 0; mf < 4; ++mf) {
            #pragma unroll
            for (int nf = 0; nf < 4; ++nf) {
                const int c2 = n0 + nf * 16 + l15;
                const int s0i = mf * 16 + l4 * 4;
                ushort4 st;
                st.x = f2bf(acc[mf][nf][0]); st.y = f2bf(acc[mf][nf][1]);
                st.z = f2bf(acc[mf][nf][2]); st.w = f2bf(acc[mf][nf][3]);
                *(ushort4*)&attT[((long)b * 1024 + c2) * 1024 + h * 64 + s0i] = st;
            }
        }
    }
}

// ---------------- launch ----------------

extern "C" void kernel_launch(void* const* d_in, const int* in_sizes, int n_in,
                              void* d_out, int out_size, void* d_ws, size_t ws_size,
                              hipStream_t stream)
{
    (void)in_sizes; (void)n_in; (void)out_size; (void)ws_size;
    const float* x   = (const float*)d_in[0];
    const float* wu  = (const float*)d_in[1];
    const float* wv  = (const float*)d_in[2];
    const float* wvb = (const float*)d_in[3];
    const float* hw  = (const float*)d_in[4];
    const float* cpw = (const float*)d_in[5];
    const float* cpb = (const float*)d_in[6];
    float* out = (float*)d_out;

    char* ws = (char*)d_ws;
    // layout (bytes):
    ushort_t* x_bf    = (ushort_t*)(ws);                        // 32 MB  [16384][1024]
    ushort_t* uvT     = (ushort_t*)(ws + 33554432L);            // 64 MB  [2048][16384]  (transposed uv)
    ushort_t* yT      = uvT;                                    // 32 MB, reuses uvT after k_attn_s
    ushort_t* attT    = (ushort_t*)(ws + 100663296L);           // 16 MB  [8][1024][1024]
    float*    Sp      = (float*)   (ws + 117440512L);           // 4 MB   [2][8][16][64][64] f32 partial S
    ushort_t* wcat    = (ushort_t*)(ws + 117440512L);           // 4 MB   (dead after K1; overlaid by Sp)
    ushort_t* helperT = (ushort_t*)(ws + 121634816L);           // 128 KB
    ushort_t* cproj   = (ushort_t*)(ws + 121765888L);           // 2 MB
    float*    bias1   = (float*)   (ws + 123863040L);           // 8 KB

    // prep
    k_conv_x4      <<<2048, 256, 0, stream>>>((const float4*)x, (ushort4*)x_bf, 4194304);
    k_prep_wcat    <<<2048, 256, 0, stream>>>(wu, wv, wcat, 2097152);
    k_prep_bias1   <<<8, 256, 0, stream>>>(wvb, bias1);
    k_prep_helperT <<<256, 256, 0, stream>>>(hw, helperT);
    k_conv_f32_bf16<<<2048, 256, 0, stream>>>(cpw, cproj, 1048576);

    // K1: uvT = (x @ [w_u; w_v]^T + [0; b_v])^T   (M=16384, N=2048, K=1024 -> C^T [2048][16384])
    {
        dim3 g(128, 16, 1);
        k_gemm_bt<2><<<g, 256, 0, stream>>>(x_bf, wcat, uvT, bias1,
                                            1024, 1024, 1024, 16384, 0, 0, 0);
    }
    // K2a: partial S per (h, b, k-half)
    {
        dim3 g(16, 8, 2);
        k_attn_s<<<g, 256, 0, stream>>>(uvT, Sp);
    }
    // K2b: combine + softmax + P@helper -> attT
    {
        dim3 g(16, 8, 1);
        k_attn_f<<<g, 256, 0, stream>>>(Sp, helperT, attT);
    }
    // K3: yT[b] = attT[b] @ x[b]^T   (M=1024, N=2048, K=1024, batched over b)
    {
        dim3 g(8, 16, 8);
        k_gemm_bt<0><<<g, 256, 0, stream>>>(attT, x_bf, yT, nullptr,
                                            1024, 1024, 1024, 2048,
                                            1048576L, 2097152L, 2097152L);
    }
    // K4: out = Z @ c_proj^T + b   (Z = yT flat [16384][1024], fp32 out)
    {
        dim3 g(128, 8, 1);
        k_gemm_bt<1><<<g, 256, 0, stream>>>(yT, cproj, (void*)out, cpb,
                                            1024, 1024, 1024, 1024, 0, 0, 0);
    }
}

// Round 3
// 212.218 us; speedup vs baseline: 1.5166x; 1.2643x over previous
//
#include <hip/hip_runtime.h>

typedef unsigned short ushort_t;
typedef __bf16 bf16x8 __attribute__((ext_vector_type(8)));
typedef float f32x4 __attribute__((ext_vector_type(4)));

__device__ __forceinline__ ushort_t f2bf(float f) {
    unsigned u = __builtin_bit_cast(unsigned, f);
    unsigned r = (u + 0x7fffu + ((u >> 16) & 1u)) >> 16;
    return (ushort_t)r;
}

__device__ __forceinline__ void async16(const ushort_t* g, void* lds) {
    __builtin_amdgcn_global_load_lds(
        (const __attribute__((address_space(1))) void*)g,
        (__attribute__((address_space(3))) void*)lds, 16, 0, 0);
}

// ---------------- prep kernels ----------------

__global__ void k_conv_x4(const float4* __restrict__ in, ushort4* __restrict__ out, int n4) {
    int i = blockIdx.x * blockDim.x + threadIdx.x;
    int st = gridDim.x * blockDim.x;
    for (; i < n4; i += st) {
        float4 f = in[i];
        ushort4 o;
        o.x = f2bf(f.x); o.y = f2bf(f.y); o.z = f2bf(f.z); o.w = f2bf(f.w);
        out[i] = o;
    }
}

__global__ void k_conv_f32_bf16(const float* __restrict__ in, ushort_t* __restrict__ out, int n) {
    int i = blockIdx.x * blockDim.x + threadIdx.x;
    int st = gridDim.x * blockDim.x;
    for (; i < n; i += st) out[i] = f2bf(in[i]);
}

__global__ void k_prep_wcat(const float* __restrict__ wu, const float* __restrict__ wv,
                            ushort_t* __restrict__ wcat, int n) {
    int i = blockIdx.x * blockDim.x + threadIdx.x;
    int st = gridDim.x * blockDim.x;
    for (; i < n; i += st)
        wcat[i] = f2bf(i < 1048576 ? wu[i] : wv[i - 1048576]);
}

__global__ void k_prep_bias1(const float* __restrict__ wvb, float* __restrict__ bias1) {
    int i = blockIdx.x * blockDim.x + threadIdx.x;
    if (i < 2048) bias1[i] = (i < 1024) ? 0.0f : wvb[i - 1024];
}

__global__ void k_prep_helperT(const float* __restrict__ hw, ushort_t* __restrict__ hT) {
    int i = blockIdx.x * blockDim.x + threadIdx.x;
    if (i < 65536) {
        int c = i >> 6, d = i & 63;
        hT[i] = f2bf(hw[d * 1024 + c]);   // helperT[c][d] = helper_w[d][c]
    }
}

// ---------------- main GEMM: C[m,n] = sum_k A[m,k] * Bt[n,k] (+bias[n]) ----------------
// 128x128 tile, BK=64, XOR-swizzled LDS (conflict-free), 4 waves, 64x64 quadrant each.
// OUT_MODE: 0 = bf16 row-major, 1 = f32 row-major,
//           2 = bf16 transposed (C^T[n][m], ldC = C^T row len)
//           3 = f32 interleaved: out[(z>>1)*2048 + 2*row + (z&1)][col] (+bias[col])

template<int OUT_MODE>
__global__ __launch_bounds__(256)
void k_gemm_bt(const ushort_t* __restrict__ A, const ushort_t* __restrict__ Bt,
               void* __restrict__ Cv, const float* __restrict__ bias,
               int K, int ldA, int ldB, int ldC,
               long sA, long sB, long sC)
{
    __shared__ ushort_t smem[16896];     // staging: As=smem[0:8192], Bs=smem[8192:16384]; epilogue: 128x132
    ushort_t* As = smem;                 // [128 rows][64 k] bf16, 128B rows, chunk-swizzled
    ushort_t* Bs = smem + 8192;
    const int z = blockIdx.z;
    const ushort_t* Ab = A + (long)z * sA;
    const ushort_t* Bb = Bt + (long)z * sB;
    const int m0 = blockIdx.x * 128;
    const int n0 = blockIdx.y * 128;
    const int tid = threadIdx.x;
    const int w = tid >> 6;
    const int lane = tid & 63;
    const int l15 = lane & 15, l4 = lane >> 4;
    const int wr = (w >> 1) * 64, wc = (w & 1) * 64;

    f32x4 acc[4][4] = {};

    const int srow = lane >> 3;                  // 0..7
    const int gchunk = (lane & 7) ^ srow;        // pre-swizzled global 16B-chunk index

    for (int kt = 0; kt < K; kt += 64) {
        __syncthreads();
        #pragma unroll
        for (int q = 0; q < 4; ++q) {
            const int seg = w * 4 + q;           // 0..15, wave-uniform
            const int r = seg * 8 + srow;        // 0..127
            async16(Ab + (long)(m0 + r) * ldA + kt + gchunk * 8, (char*)As + seg * 1024);
            async16(Bb + (long)(n0 + r) * ldB + kt + gchunk * 8, (char*)Bs + seg * 1024);
        }
        __syncthreads();
        #pragma unroll
        for (int kk = 0; kk < 2; ++kk) {
            bf16x8 af[4], bfr[4];
            const int swz = ((kk * 4 + l4) ^ (l15 & 7)) * 8;
            #pragma unroll
            for (int i = 0; i < 4; ++i) {
                af[i]  = *(const bf16x8*)&As[(wr + i * 16 + l15) * 64 + swz];
                bfr[i] = *(const bf16x8*)&Bs[(wc + i * 16 + l15) * 64 + swz];
            }
            #pragma unroll
            for (int i = 0; i < 4; ++i)
                #pragma unroll
                for (int j = 0; j < 4; ++j)
                    acc[i][j] = __builtin_amdgcn_mfma_f32_16x16x32_bf16(af[i], bfr[j], acc[i][j], 0, 0, 0);
        }
    }

    if (OUT_MODE == 2) {
        __syncthreads();
        #pragma unroll
        for (int i = 0; i < 4; ++i) {
            #pragma unroll
            for (int j = 0; j < 4; ++j) {
                const int n = wc + j * 16 + l15;
                const float bv = bias ? bias[n0 + n] : 0.0f;
                #pragma unroll
                for (int e = 0; e < 4; ++e) {
                    const int m = wr + i * 16 + l4 * 4 + e;
                    smem[m * 132 + n] = f2bf(acc[i][j][e] + bv);
                }
            }
        }
        __syncthreads();
        const int nr = tid & 127;
        const int mh = tid >> 7;
        ushort_t* Ct = (ushort_t*)Cv;
        #pragma unroll
        for (int v = 0; v < 8; ++v) {
            uint4 pk;
            unsigned* pw = (unsigned*)&pk;
            #pragma unroll
            for (int p2 = 0; p2 < 4; ++p2) {
                const int m = mh * 64 + v * 8 + p2 * 2;
                unsigned lo = smem[m * 132 + nr];
                unsigned hi = smem[(m + 1) * 132 + nr];
                pw[p2] = lo | (hi << 16);
            }
            *(uint4*)&Ct[(long)(n0 + nr) * ldC + m0 + mh * 64 + v * 8] = pk;
        }
    } else if (OUT_MODE == 3) {
        const int bb_ = z >> 1, pp_ = z & 1;
        float* O = (float*)Cv + (long)bb_ * 2097152 + (long)pp_ * 1024;
        #pragma unroll
        for (int i = 0; i < 4; ++i) {
            #pragma unroll
            for (int j = 0; j < 4; ++j) {
                const int row0 = m0 + wr + i * 16 + l4 * 4;     // c index
                const int col  = n0 + wc + j * 16 + l15;        // o index
                const float bv = bias[col];
                #pragma unroll
                for (int e = 0; e < 4; ++e)
                    O[(long)(row0 + e) * 2048 + col] = acc[i][j][e] + bv;
            }
        }
    } else {
        #pragma unroll
        for (int i = 0; i < 4; ++i) {
            #pragma unroll
            for (int j = 0; j < 4; ++j) {
                const int row0 = m0 + wr + i * 16 + l4 * 4;
                const int col  = n0 + wc + j * 16 + l15;
                const float bv = bias ? bias[col] : 0.0f;
                #pragma unroll
                for (int e = 0; e < 4; ++e) {
                    float vv = acc[i][j][e] + bv;
                    if (OUT_MODE == 1)
                        ((float*)Cv)[(long)z * sC + (long)(row0 + e) * ldC + col] = vv;
                    else
                        ((ushort_t*)Cv)[(long)z * sC + (long)(row0 + e) * ldC + col] = f2bf(vv);
                }
            }
        }
    }
}

// ---------------- skinny GEMM: 128(M) x 64(N) tile, K=1024, Bt [64][K] from global ----------------
// MODE 0: G = x @ PstackT  (A=x_bf flat rows, Bt=PT[b] selected by m0; OUTPUT TRANSPOSED -> GT[64][16384])
// MODE 1: Q = cproj @ Gp   (A=cproj, Bt=GT+z*1024 ldB=16384; output Q[z][o][d] row-major)

template<int MODE>
__global__ __launch_bounds__(256)
void k_skinny(const ushort_t* __restrict__ A, const ushort_t* __restrict__ Bt,
              ushort_t* __restrict__ C)
{
    __shared__ ushort_t smem[128 * 68];   // As uses first 8192 elems; MODE0 epilogue uses [128][68]
    ushort_t* As = smem;
    const int tid = threadIdx.x;
    const int w = tid >> 6, lane = tid & 63;
    const int l15 = lane & 15, l4 = lane >> 4;
    const int m0 = blockIdx.x * 128;
    const int z = blockIdx.z;

    const ushort_t* Ab;
    const ushort_t* Bb;
    int ldB;
    if (MODE == 0) { Ab = A + (long)m0 * 1024; Bb = Bt + (long)(m0 >> 11) * 65536; ldB = 1024; }
    else           { Ab = A + (long)m0 * 1024; Bb = Bt + (long)z * 1024;           ldB = 16384; }

    f32x4 acc[2][4] = {};
    const int srow = lane >> 3;
    const int gchunk = (lane & 7) ^ srow;

    for (int kt = 0; kt < 1024; kt += 64) {
        __syncthreads();
        #pragma unroll
        for (int q = 0; q < 4; ++q) {
            const int seg = w * 4 + q;
            async16(Ab + (long)(seg * 8 + srow) * 1024 + kt + gchunk * 8, (char*)As + seg * 1024);
        }
        __syncthreads();
        #pragma unroll
        for (int kk = 0; kk < 2; ++kk) {
            const int swz = ((kk * 4 + l4) ^ (l15 & 7)) * 8;
            bf16x8 af[2], bfr[4];
            #pragma unroll
            for (int i = 0; i < 2; ++i)
                af[i] = *(const bf16x8*)&As[(w * 32 + i * 16 + l15) * 64 + swz];
            #pragma unroll
            for (int nf = 0; nf < 4; ++nf)
                bfr[nf] = *(const bf16x8*)&Bb[(long)(nf * 16 + l15) * ldB + kt + kk * 32 + l4 * 8];
            #pragma unroll
            for (int i = 0; i < 2; ++i)
                #pragma unroll
                for (int nf = 0; nf < 4; ++nf)
                    acc[i][nf] = __builtin_amdgcn_mfma_f32_16x16x32_bf16(af[i], bfr[nf], acc[i][nf], 0, 0, 0);
        }
    }

    if (MODE == 0) {
        // transpose epilogue: smem[m][d] (pad 68) -> GT[d][m0+m]
        __syncthreads();
        #pragma unroll
        for (int i = 0; i < 2; ++i)
            #pragma unroll
            for (int nf = 0; nf < 4; ++nf)
                #pragma unroll
                for (int e = 0; e < 4; ++e)
                    smem[(w * 32 + i * 16 + l4 * 4 + e) * 68 + nf * 16 + l15] = f2bf(acc[i][nf][e]);
        __syncthreads();
        const int d = tid >> 2, qq = tid & 3;
        unsigned wds[16];
        #pragma unroll
        for (int u2 = 0; u2 < 16; ++u2) {
            unsigned lo = smem[(qq * 32 + 2 * u2) * 68 + d];
            unsigned hi = smem[(qq * 32 + 2 * u2 + 1) * 68 + d];
            wds[u2] = lo | (hi << 16);
        }
        #pragma unroll
        for (int v = 0; v < 4; ++v) {
            uint4 pk; unsigned* pw = (unsigned*)&pk;
            pw[0] = wds[v * 4]; pw[1] = wds[v * 4 + 1]; pw[2] = wds[v * 4 + 2]; pw[3] = wds[v * 4 + 3];
            *(uint4*)&C[(long)d * 16384 + m0 + qq * 32 + v * 8] = pk;
        }
    } else {
        ushort_t* Co = C + (long)z * 65536;
        #pragma unroll
        for (int i = 0; i < 2; ++i)
            #pragma unroll
            for (int nf = 0; nf < 4; ++nf)
                #pragma unroll
                for (int e = 0; e < 4; ++e)
                    Co[(long)(m0 + w * 32 + i * 16 + l4 * 4 + e) * 64 + nf * 16 + l15] = f2bf(acc[i][nf][e]);
    }
}

// ---------------- attention part 1: partial S from uvT (no LDS) ----------------

__global__ __launch_bounds__(256)
void k_attn_s(const ushort_t* __restrict__ uvT, float* __restrict__ Sp)
{
    const int h = blockIdx.x, b = blockIdx.y, kq = blockIdx.z;
    const int tid = threadIdx.x;
    const int w = tid >> 6, lane = tid & 63;
    const int l15 = lane & 15, l4 = lane >> 4;

    f32x4 sf[4] = {};
    const long tbase = (long)b * 2048 + kq * 1024 + l4 * 8;
    const ushort_t* pa  = uvT + (long)(h * 64 + w * 16 + l15) * 16384 + tbase;
    const ushort_t* pb0 = uvT + (long)(1024 + h * 64 + l15) * 16384 + tbase;

    #pragma unroll 2
    for (int kt = 0; kt < 1024; kt += 32) {
        bf16x8 a = *(const bf16x8*)(pa + kt);
        #pragma unroll
        for (int nf = 0; nf < 4; ++nf) {
            bf16x8 bb = *(const bf16x8*)(pb0 + (long)(nf * 16) * 16384 + kt);
            sf[nf] = __builtin_amdgcn_mfma_f32_16x16x32_bf16(a, bb, sf[nf], 0, 0, 0);
        }
    }

    float* outp = Sp + (long)((kq * 8 + b) * 16 + h) * 4096;
    #pragma unroll
    for (int nf = 0; nf < 4; ++nf)
        #pragma unroll
        for (int j = 0; j < 4; ++j)
            outp[(w * 16 + l4 * 4 + j) * 64 + nf * 16 + l15] = sf[nf][j];
}

// ---------------- attention part 2: sum partials, softmax -> PstackT ----------------
// PT[b][d][h*64+s] = P[b,h][s][d]

__global__ __launch_bounds__(256)
void k_attn_f(const float* __restrict__ Sp, ushort_t* __restrict__ PT)
{
    __shared__ ushort_t PA[64 * 72];
    const int h = blockIdx.x, b = blockIdx.y;
    const int tid = threadIdx.x;
    const int w = tid >> 6, lane = tid & 63;
    const int l15 = lane & 15, l4 = lane >> 4;

    const float* s0 = Sp + (long)((0 * 8 + b) * 16 + h) * 4096;
    const float* s1 = Sp + (long)((1 * 8 + b) * 16 + h) * 4096;

    const float scale = 0.03125f;   // 1/sqrt(1024)
    const int rb = w * 16 + l4 * 4;
    #pragma unroll
    for (int j = 0; j < 4; ++j) {
        const int srowi = rb + j;
        float v[4];
        #pragma unroll
        for (int nf = 0; nf < 4; ++nf) {
            const int col = nf * 16 + l15;
            const int idx = srowi * 64 + col;
            const float sv = s0[idx] + s1[idx];
            v[nf] = (col <= srowi) ? sv * scale : -3.0e38f;
        }
        float mx = fmaxf(fmaxf(v[0], v[1]), fmaxf(v[2], v[3]));
        #pragma unroll
        for (int o = 1; o < 16; o <<= 1) mx = fmaxf(mx, __shfl_xor(mx, o, 64));
        float s = 0.0f;
        #pragma unroll
        for (int nf = 0; nf < 4; ++nf) { v[nf] = __expf(v[nf] - mx); s += v[nf]; }
        #pragma unroll
        for (int o = 1; o < 16; o <<= 1) s += __shfl_xor(s, o, 64);
        const float inv = 1.0f / s;
        #pragma unroll
        for (int nf = 0; nf < 4; ++nf)
            PA[srowi * 72 + nf * 16 + l15] = f2bf(v[nf] * inv);
    }
    __syncthreads();

    // transpose out of PA: thread -> (d = tid>>2, quarter qq = tid&3), write 16 c1-contig elems
    const int d = tid >> 2, qq = tid & 3;
    unsigned wds[8];
    #pragma unroll
    for (int u2 = 0; u2 < 8; ++u2) {
        unsigned lo = PA[(qq * 16 + 2 * u2) * 72 + d];
        unsigned hi = PA[(qq * 16 + 2 * u2 + 1) * 72 + d];
        wds[u2] = lo | (hi << 16);
    }
    ushort_t* dst = PT + ((long)b * 64 + d) * 1024 + h * 64 + qq * 16;
    uint4 p0; unsigned* q0 = (unsigned*)&p0;
    q0[0] = wds[0]; q0[1] = wds[1]; q0[2] = wds[2]; q0[3] = wds[3];
    uint4 p1; unsigned* q1 = (unsigned*)&p1;
    q1[0] = wds[4]; q1[1] = wds[5]; q1[2] = wds[6]; q1[3] = wds[7];
    *(uint4*)dst = p0;
    *(uint4*)(dst + 8) = p1;
}

// ---------------- launch ----------------

extern "C" void kernel_launch(void* const* d_in, const int* in_sizes, int n_in,
                              void* d_out, int out_size, void* d_ws, size_t ws_size,
                              hipStream_t stream)
{
    (void)in_sizes; (void)n_in; (void)out_size; (void)ws_size;
    const float* x   = (const float*)d_in[0];
    const float* wu  = (const float*)d_in[1];
    const float* wv  = (const float*)d_in[2];
    const float* wvb = (const float*)d_in[3];
    const float* hw  = (const float*)d_in[4];
    const float* cpw = (const float*)d_in[5];
    const float* cpb = (const float*)d_in[6];
    float* out = (float*)d_out;

    char* ws = (char*)d_ws;
    ushort_t* x_bf    = (ushort_t*)(ws);                        // 32 MB  [16384][1024]
    ushort_t* uvT     = (ushort_t*)(ws + 33554432L);            // 64 MB  [2048][16384]
    ushort_t* GT      = (ushort_t*)(ws + 100663296L);           // 2 MB   [64][16384]
    ushort_t* Q       = (ushort_t*)(ws + 102760448L);           // 2 MB   [16][1024][64]
    ushort_t* PT      = (ushort_t*)(ws + 104857600L);           // 1 MB   [8][64][1024]
    float*    Sp      = (float*)   (ws + 117440512L);           // 4 MB   (overlays wcat, dead after K1)
    ushort_t* wcat    = (ushort_t*)(ws + 117440512L);           // 4 MB
    ushort_t* helperT = (ushort_t*)(ws + 121634816L);           // 128 KB [1024][64]
    ushort_t* cproj   = (ushort_t*)(ws + 121765888L);           // 2 MB   [1024][1024]
    float*    bias1   = (float*)   (ws + 123863040L);           // 8 KB

    // prep
    k_conv_x4      <<<2048, 256, 0, stream>>>((const float4*)x, (ushort4*)x_bf, 4194304);
    k_prep_wcat    <<<2048, 256, 0, stream>>>(wu, wv, wcat, 2097152);
    k_prep_bias1   <<<8, 256, 0, stream>>>(wvb, bias1);
    k_prep_helperT <<<256, 256, 0, stream>>>(hw, helperT);
    k_conv_f32_bf16<<<2048, 256, 0, stream>>>(cpw, cproj, 1048576);

    // K1: uvT = (x @ [w_u; w_v]^T + [0; b_v])^T   -> [2048][16384]
    {
        dim3 g(128, 16, 1);
        k_gemm_bt<2><<<g, 256, 0, stream>>>(x_bf, wcat, uvT, bias1,
                                            1024, 1024, 1024, 16384, 0, 0, 0);
    }
    // K2a: partial S per (h, b, k-half)
    {
        dim3 g(16, 8, 2);
        k_attn_s<<<g, 256, 0, stream>>>(uvT, Sp);
    }
    // K2b: combine + softmax -> PstackT [8][64][1024]
    {
        dim3 g(16, 8, 1);
        k_attn_f<<<g, 256, 0, stream>>>(Sp, PT);
    }
    // K3a: GT[d][b*2048+t] = (x[b] @ Pstack[b])^T   (M=16384 rows of x, N=64)
    {
        dim3 g(128, 1, 1);
        k_skinny<0><<<g, 256, 0, stream>>>(x_bf, PT, GT);
    }
    // K3b: Q[sidx] = c_proj @ G[sidx-half]   (M=1024 o, N=64 d, K=1024; sidx = b*2+p)
    {
        dim3 g(8, 1, 16);
        k_skinny<1><<<g, 256, 0, stream>>>(cproj, GT, Q);
    }
    // K4: out[b][2c+p][o] = helperT[c][:] . Q[sidx][o][:] + cpb[o]   (M=1024 c, N=1024 o, K=64)
    {
        dim3 g(8, 8, 16);
        k_gemm_bt<3><<<g, 256, 0, stream>>>(helperT, Q, (void*)out, cpb,
                                            64, 64, 64, 0, 0, 65536L, 0);
    }
}

// Round 4
// 210.511 us; speedup vs baseline: 1.5289x; 1.0081x over previous
//
#include <hip/hip_runtime.h>

typedef unsigned short ushort_t;
typedef __bf16 bf16x8 __attribute__((ext_vector_type(8)));
typedef float f32x4 __attribute__((ext_vector_type(4)));

__device__ __forceinline__ ushort_t f2bf(float f) {
    unsigned u = __builtin_bit_cast(unsigned, f);
    unsigned r = (u + 0x7fffu + ((u >> 16) & 1u)) >> 16;
    return (ushort_t)r;
}

__device__ __forceinline__ void async16(const ushort_t* g, void* lds) {
    __builtin_amdgcn_global_load_lds(
        (const __attribute__((address_space(1))) void*)g,
        (__attribute__((address_space(3))) void*)lds, 16, 0, 0);
}

// ---------------- prep kernels ----------------

__global__ void k_conv_f32_bf16(const float* __restrict__ in, ushort_t* __restrict__ out, int n) {
    int i = blockIdx.x * blockDim.x + threadIdx.x;
    int st = gridDim.x * blockDim.x;
    for (; i < n; i += st) out[i] = f2bf(in[i]);
}

__global__ void k_prep_helperT(const float* __restrict__ hw, ushort_t* __restrict__ hT) {
    int i = blockIdx.x * blockDim.x + threadIdx.x;
    if (i < 65536) {
        int c = i >> 6, d = i & 63;
        hT[i] = f2bf(hw[d * 1024 + c]);   // helperT[c][d] = helper_w[d][c]
    }
}

// fused: x fp32 -> x_bf [16384][1024] AND xT_bf [8][1024][2048]
__global__ __launch_bounds__(256)
void k_trans(const float* __restrict__ x, ushort_t* __restrict__ xbf, ushort_t* __restrict__ xT)
{
    __shared__ ushort_t T[64 * 72];
    const int t0 = blockIdx.x * 64, c0 = blockIdx.y * 64, b = blockIdx.z;
    const int tid = threadIdx.x;
    const int r = tid >> 2, q = tid & 3;
    #pragma unroll
    for (int i = 0; i < 4; ++i) {
        const int cq = q + i * 4;   // 0..15 (float4 columns)
        const long gi = ((long)(b * 2048 + t0 + r)) * 1024 + c0 + cq * 4;
        float4 f = *(const float4*)&x[gi];
        ushort4 o;
        o.x = f2bf(f.x); o.y = f2bf(f.y); o.z = f2bf(f.z); o.w = f2bf(f.w);
        *(ushort4*)&xbf[gi] = o;
        *(ushort4*)&T[r * 72 + cq * 4] = o;
    }
    __syncthreads();
    const int cl = tid >> 2, tq = tid & 3;
    #pragma unroll
    for (int i = 0; i < 4; ++i) {
        const int tc = tq + i * 4;  // 0..15 (chunks of 4 t)
        ushort4 o;
        o.x = T[(tc * 4 + 0) * 72 + cl];
        o.y = T[(tc * 4 + 1) * 72 + cl];
        o.z = T[(tc * 4 + 2) * 72 + cl];
        o.w = T[(tc * 4 + 3) * 72 + cl];
        *(ushort4*)&xT[((long)(b * 1024 + c0 + cl)) * 2048 + t0 + tc * 4] = o;
    }
}

// column sums: xsum[b][c] = sum_t x[b][t][c], read from xT rows
__global__ __launch_bounds__(256)
void k_xsum(const ushort_t* __restrict__ xT, float* __restrict__ xsum)
{
    const int tid = threadIdx.x, w = tid >> 6, lane = tid & 63;
    const int b = blockIdx.y, c = blockIdx.x * 4 + w;
    const ushort_t* p = xT + ((long)b * 1024 + c) * 2048 + lane * 8;
    float s = 0.0f;
    #pragma unroll
    for (int i = 0; i < 4; ++i) {
        bf16x8 v = *(const bf16x8*)(p + i * 512);
        #pragma unroll
        for (int j = 0; j < 8; ++j) s += (float)v[j];
    }
    #pragma unroll
    for (int o = 1; o < 64; o <<= 1) s += __shfl_xor(s, o, 64);
    if (lane == 0) xsum[b * 1024 + c] = s;
}

// s_u[b][hs] = dot(w_u[hs,:], xsum[b,:])
__global__ __launch_bounds__(256)
void k_su(const ushort_t* __restrict__ wu, const float* __restrict__ xsum,
          float* __restrict__ su)
{
    const int tid = threadIdx.x, w = tid >> 6, lane = tid & 63;
    const int b = blockIdx.y, hs = blockIdx.x * 4 + w;
    const ushort_t* pw = wu + (long)hs * 1024 + lane * 16;
    const float* px = xsum + b * 1024 + lane * 16;
    float s = 0.0f;
    #pragma unroll
    for (int i = 0; i < 2; ++i) {
        bf16x8 a = *(const bf16x8*)(pw + i * 8);
        float4 f0 = *(const float4*)(px + i * 8);
        float4 f1 = *(const float4*)(px + i * 8 + 4);
        s += (float)a[0] * f0.x + (float)a[1] * f0.y + (float)a[2] * f0.z + (float)a[3] * f0.w
           + (float)a[4] * f1.x + (float)a[5] * f1.y + (float)a[6] * f1.z + (float)a[7] * f1.w;
    }
    #pragma unroll
    for (int o = 1; o < 64; o <<= 1) s += __shfl_xor(s, o, 64);
    if (lane == 0) su[b * 1024 + hs] = s;
}

// ---------------- main GEMM: C[m,n] = sum_k A[m,k] * Bt[n,k] (+bias[n]) ----------------
// 128x128 tile, BK=64, XOR-swizzled LDS, 4 waves.
// OUT_MODE: 0 = bf16 row-major, 3 = f32 interleaved out[(z>>1)*2048 + 2*row + (z&1)][col]

template<int OUT_MODE>
__global__ __launch_bounds__(256)
void k_gemm_bt(const ushort_t* __restrict__ A, const ushort_t* __restrict__ Bt,
               void* __restrict__ Cv, const float* __restrict__ bias,
               int K, int ldA, int ldB, int ldC,
               long sA, long sB, long sC)
{
    __shared__ ushort_t smem[16896];
    ushort_t* As = smem;
    ushort_t* Bs = smem + 8192;
    const int z = blockIdx.z;
    const ushort_t* Ab = A + (long)z * sA;
    const ushort_t* Bb = Bt + (long)z * sB;
    const int m0 = blockIdx.x * 128;
    const int n0 = blockIdx.y * 128;
    const int tid = threadIdx.x;
    const int w = tid >> 6;
    const int lane = tid & 63;
    const int l15 = lane & 15, l4 = lane >> 4;
    const int wr = (w >> 1) * 64, wc = (w & 1) * 64;

    f32x4 acc[4][4] = {};
    const int srow = lane >> 3;
    const int gchunk = (lane & 7) ^ srow;

    for (int kt = 0; kt < K; kt += 64) {
        __syncthreads();
        #pragma unroll
        for (int q = 0; q < 4; ++q) {
            const int seg = w * 4 + q;
            const int r = seg * 8 + srow;
            async16(Ab + (long)(m0 + r) * ldA + kt + gchunk * 8, (char*)As + seg * 1024);
            async16(Bb + (long)(n0 + r) * ldB + kt + gchunk * 8, (char*)Bs + seg * 1024);
        }
        __syncthreads();
        #pragma unroll
        for (int kk = 0; kk < 2; ++kk) {
            bf16x8 af[4], bfr[4];
            const int swz = ((kk * 4 + l4) ^ (l15 & 7)) * 8;
            #pragma unroll
            for (int i = 0; i < 4; ++i) {
                af[i]  = *(const bf16x8*)&As[(wr + i * 16 + l15) * 64 + swz];
                bfr[i] = *(const bf16x8*)&Bs[(wc + i * 16 + l15) * 64 + swz];
            }
            #pragma unroll
            for (int i = 0; i < 4; ++i)
                #pragma unroll
                for (int j = 0; j < 4; ++j)
                    acc[i][j] = __builtin_amdgcn_mfma_f32_16x16x32_bf16(af[i], bfr[j], acc[i][j], 0, 0, 0);
        }
    }

    if (OUT_MODE == 3) {
        const int bb_ = z >> 1, pp_ = z & 1;
        float* O = (float*)Cv + (long)bb_ * 2097152 + (long)pp_ * 1024;
        #pragma unroll
        for (int i = 0; i < 4; ++i) {
            #pragma unroll
            for (int j = 0; j < 4; ++j) {
                const int row0 = m0 + wr + i * 16 + l4 * 4;
                const int col  = n0 + wc + j * 16 + l15;
                const float bv = bias[col];
                #pragma unroll
                for (int e = 0; e < 4; ++e)
                    O[(long)(row0 + e) * 2048 + col] = acc[i][j][e] + bv;
            }
        }
    } else {
        #pragma unroll
        for (int i = 0; i < 4; ++i) {
            #pragma unroll
            for (int j = 0; j < 4; ++j) {
                const int row0 = m0 + wr + i * 16 + l4 * 4;
                const int col  = n0 + wc + j * 16 + l15;
                const float bv = bias ? bias[col] : 0.0f;
                #pragma unroll
                for (int e = 0; e < 4; ++e)
                    ((ushort_t*)Cv)[(long)z * sC + (long)(row0 + e) * ldC + col] = f2bf(acc[i][j][e] + bv);
            }
        }
    }
}

// ---------------- SYRK: XtX[b] = xT[b] @ xT[b]^T (symmetric), upper-tri blocks + mirror ----------------

__global__ __launch_bounds__(256)
void k_syrk(const ushort_t* __restrict__ xT, ushort_t* __restrict__ XtX)
{
    __shared__ ushort_t smem[16896];
    ushort_t* As = smem;
    ushort_t* Bs = smem + 8192;
    const int z = blockIdx.z;
    int L = blockIdx.x, bi = 0;
    while (L >= 8 - bi) { L -= 8 - bi; ++bi; }
    const int bj = bi + L;
    const ushort_t* base = xT + (long)z * 2097152;   // [1024][2048]
    const ushort_t* Ab = base + (long)bi * 128 * 2048;
    const ushort_t* Bb = base + (long)bj * 128 * 2048;
    ushort_t* C = XtX + (long)z * 1048576;           // [1024][1024]
    const int tid = threadIdx.x;
    const int w = tid >> 6;
    const int lane = tid & 63;
    const int l15 = lane & 15, l4 = lane >> 4;
    const int wr = (w >> 1) * 64, wc = (w & 1) * 64;

    f32x4 acc[4][4] = {};
    const int srow = lane >> 3;
    const int gchunk = (lane & 7) ^ srow;

    for (int kt = 0; kt < 2048; kt += 64) {
        __syncthreads();
        #pragma unroll
        for (int q = 0; q < 4; ++q) {
            const int seg = w * 4 + q;
            const int r = seg * 8 + srow;
            async16(Ab + (long)r * 2048 + kt + gchunk * 8, (char*)As + seg * 1024);
            async16(Bb + (long)r * 2048 + kt + gchunk * 8, (char*)Bs + seg * 1024);
        }
        __syncthreads();
        #pragma unroll
        for (int kk = 0; kk < 2; ++kk) {
            bf16x8 af[4], bfr[4];
            const int swz = ((kk * 4 + l4) ^ (l15 & 7)) * 8;
            #pragma unroll
            for (int i = 0; i < 4; ++i) {
                af[i]  = *(const bf16x8*)&As[(wr + i * 16 + l15) * 64 + swz];
                bfr[i] = *(const bf16x8*)&Bs[(wc + i * 16 + l15) * 64 + swz];
            }
            #pragma unroll
            for (int i = 0; i < 4; ++i)
                #pragma unroll
                for (int j = 0; j < 4; ++j)
                    acc[i][j] = __builtin_amdgcn_mfma_f32_16x16x32_bf16(af[i], bfr[j], acc[i][j], 0, 0, 0);
        }
    }

    // normal write at (bi*128 + m, bj*128 + n)
    #pragma unroll
    for (int i = 0; i < 4; ++i) {
        #pragma unroll
        for (int j = 0; j < 4; ++j) {
            const int row0 = bi * 128 + wr + i * 16 + l4 * 4;
            const int col  = bj * 128 + wc + j * 16 + l15;
            #pragma unroll
            for (int e = 0; e < 4; ++e)
                C[(long)(row0 + e) * 1024 + col] = f2bf(acc[i][j][e]);
        }
    }
    if (bi != bj) {
        // mirror: stage bf16 tile [m][n] in LDS, write transposed rows
        __syncthreads();
        #pragma unroll
        for (int i = 0; i < 4; ++i)
            #pragma unroll
            for (int j = 0; j < 4; ++j)
                #pragma unroll
                for (int e = 0; e < 4; ++e)
                    smem[(wr + i * 16 + l4 * 4 + e) * 132 + wc + j * 16 + l15] = f2bf(acc[i][j][e]);
        __syncthreads();
        const int nr = tid & 127;      // n index (row of mirrored tile)
        const int mh = tid >> 7;       // m half
        #pragma unroll
        for (int v = 0; v < 8; ++v) {
            uint4 pk;
            unsigned* pw = (unsigned*)&pk;
            #pragma unroll
            for (int p2 = 0; p2 < 4; ++p2) {
                const int m = mh * 64 + v * 8 + p2 * 2;
                unsigned lo = smem[m * 132 + nr];
                unsigned hi = smem[(m + 1) * 132 + nr];
                pw[p2] = lo | (hi << 16);
            }
            *(uint4*)&C[(long)(bj * 128 + nr) * 1024 + bi * 128 + mh * 64 + v * 8] = pk;
        }
    }
}

// ---------------- skinny GEMM: 128(M) x 64(N) tile, K=1024 ----------------
// MODE 0: G = x @ PstackT  -> GT[64][16384] (transposed out)
// MODE 1: Q = cproj @ Gp   -> Q[z][o][d] row-major

template<int MODE>
__global__ __launch_bounds__(256)
void k_skinny(const ushort_t* __restrict__ A, const ushort_t* __restrict__ Bt,
              ushort_t* __restrict__ C)
{
    __shared__ ushort_t smem[128 * 68];
    ushort_t* As = smem;
    const int tid = threadIdx.x;
    const int w = tid >> 6, lane = tid & 63;
    const int l15 = lane & 15, l4 = lane >> 4;
    const int m0 = blockIdx.x * 128;
    const int z = blockIdx.z;

    const ushort_t* Ab;
    const ushort_t* Bb;
    int ldB;
    if (MODE == 0) { Ab = A + (long)m0 * 1024; Bb = Bt + (long)(m0 >> 11) * 65536; ldB = 1024; }
    else           { Ab = A + (long)m0 * 1024; Bb = Bt + (long)z * 1024;           ldB = 16384; }

    f32x4 acc[2][4] = {};
    const int srow = lane >> 3;
    const int gchunk = (lane & 7) ^ srow;

    for (int kt = 0; kt < 1024; kt += 64) {
        __syncthreads();
        #pragma unroll
        for (int q = 0; q < 4; ++q) {
            const int seg = w * 4 + q;
            async16(Ab + (long)(seg * 8 + srow) * 1024 + kt + gchunk * 8, (char*)As + seg * 1024);
        }
        __syncthreads();
        #pragma unroll
        for (int kk = 0; kk < 2; ++kk) {
            const int swz = ((kk * 4 + l4) ^ (l15 & 7)) * 8;
            bf16x8 af[2], bfr[4];
            #pragma unroll
            for (int i = 0; i < 2; ++i)
                af[i] = *(const bf16x8*)&As[(w * 32 + i * 16 + l15) * 64 + swz];
            #pragma unroll
            for (int nf = 0; nf < 4; ++nf)
                bfr[nf] = *(const bf16x8*)&Bb[(long)(nf * 16 + l15) * ldB + kt + kk * 32 + l4 * 8];
            #pragma unroll
            for (int i = 0; i < 2; ++i)
                #pragma unroll
                for (int nf = 0; nf < 4; ++nf)
                    acc[i][nf] = __builtin_amdgcn_mfma_f32_16x16x32_bf16(af[i], bfr[nf], acc[i][nf], 0, 0, 0);
        }
    }

    if (MODE == 0) {
        __syncthreads();
        #pragma unroll
        for (int i = 0; i < 2; ++i)
            #pragma unroll
            for (int nf = 0; nf < 4; ++nf)
                #pragma unroll
                for (int e = 0; e < 4; ++e)
                    smem[(w * 32 + i * 16 + l4 * 4 + e) * 68 + nf * 16 + l15] = f2bf(acc[i][nf][e]);
        __syncthreads();
        const int d = tid >> 2, qq = tid & 3;
        unsigned wds[16];
        #pragma unroll
        for (int u2 = 0; u2 < 16; ++u2) {
            unsigned lo = smem[(qq * 32 + 2 * u2) * 68 + d];
            unsigned hi = smem[(qq * 32 + 2 * u2 + 1) * 68 + d];
            wds[u2] = lo | (hi << 16);
        }
        #pragma unroll
        for (int v = 0; v < 4; ++v) {
            uint4 pk; unsigned* pw = (unsigned*)&pk;
            pw[0] = wds[v * 4]; pw[1] = wds[v * 4 + 1]; pw[2] = wds[v * 4 + 2]; pw[3] = wds[v * 4 + 3];
            *(uint4*)&C[(long)d * 16384 + m0 + qq * 32 + v * 8] = pk;
        }
    } else {
        ushort_t* Co = C + (long)z * 65536;
        #pragma unroll
        for (int i = 0; i < 2; ++i)
            #pragma unroll
            for (int nf = 0; nf < 4; ++nf)
                #pragma unroll
                for (int e = 0; e < 4; ++e)
                    Co[(long)(m0 + w * 32 + i * 16 + l4 * 4 + e) * 64 + nf * 16 + l15] = f2bf(acc[i][nf][e]);
    }
}

// ---------------- S-GEMM: Sp[b,h] = W2[b][h-rows] @ wv[h-rows]^T  (64x64, K=1024) ----------------

__global__ __launch_bounds__(256)
void k_attn_s2(const ushort_t* __restrict__ W2, const ushort_t* __restrict__ wv,
               float* __restrict__ Sp)
{
    const int h = blockIdx.x, b = blockIdx.y;
    const int tid = threadIdx.x;
    const int w = tid >> 6, lane = tid & 63;
    const int l15 = lane & 15, l4 = lane >> 4;

    f32x4 sf[4] = {};
    const ushort_t* pa  = W2 + (long)b * 1048576 + (long)(h * 64 + w * 16 + l15) * 1024 + l4 * 8;
    const ushort_t* pb0 = wv + (long)(h * 64 + l15) * 1024 + l4 * 8;

    #pragma unroll 2
    for (int kt = 0; kt < 1024; kt += 32) {
        bf16x8 a = *(const bf16x8*)(pa + kt);
        #pragma unroll
        for (int nf = 0; nf < 4; ++nf) {
            bf16x8 bb = *(const bf16x8*)(pb0 + (long)(nf * 16) * 1024 + kt);
            sf[nf] = __builtin_amdgcn_mfma_f32_16x16x32_bf16(a, bb, sf[nf], 0, 0, 0);
        }
    }

    float* outp = Sp + (long)(b * 16 + h) * 4096;
    #pragma unroll
    for (int nf = 0; nf < 4; ++nf)
        #pragma unroll
        for (int j = 0; j < 4; ++j)
            outp[(w * 16 + l4 * 4 + j) * 64 + nf * 16 + l15] = sf[nf][j];
}

// ---------------- softmax (+rank-1 bias) -> PstackT ----------------
// PT[b][d][h*64+s] = P[b,h][s][d]

__global__ __launch_bounds__(256)
void k_attn_f(const float* __restrict__ Sp, const float* __restrict__ su,
              const float* __restrict__ wvb, ushort_t* __restrict__ PT)
{
    __shared__ ushort_t PA[64 * 72];
    const int h = blockIdx.x, b = blockIdx.y;
    const int tid = threadIdx.x;
    const int w = tid >> 6, lane = tid & 63;
    const int l15 = lane & 15, l4 = lane >> 4;

    const float* s0 = Sp + (long)(b * 16 + h) * 4096;
    const float scale = 0.03125f;   // 1/sqrt(1024)
    const int rb = w * 16 + l4 * 4;
    #pragma unroll
    for (int j = 0; j < 4; ++j) {
        const int srowi = rb + j;
        const float suv = su[b * 1024 + h * 64 + srowi];
        float v[4];
        #pragma unroll
        for (int nf = 0; nf < 4; ++nf) {
            const int col = nf * 16 + l15;
            const float sv = s0[srowi * 64 + col] + suv * wvb[h * 64 + col];
            v[nf] = (col <= srowi) ? sv * scale : -3.0e38f;
        }
        float mx = fmaxf(fmaxf(v[0], v[1]), fmaxf(v[2], v[3]));
        #pragma unroll
        for (int o = 1; o < 16; o <<= 1) mx = fmaxf(mx, __shfl_xor(mx, o, 64));
        float s = 0.0f;
        #pragma unroll
        for (int nf = 0; nf < 4; ++nf) { v[nf] = __expf(v[nf] - mx); s += v[nf]; }
        #pragma unroll
        for (int o = 1; o < 16; o <<= 1) s += __shfl_xor(s, o, 64);
        const float inv = 1.0f / s;
        #pragma unroll
        for (int nf = 0; nf < 4; ++nf)
            PA[srowi * 72 + nf * 16 + l15] = f2bf(v[nf] * inv);
    }
    __syncthreads();

    const int d = tid >> 2, qq = tid & 3;
    unsigned wds[8];
    #pragma unroll
    for (int u2 = 0; u2 < 8; ++u2) {
        unsigned lo = PA[(qq * 16 + 2 * u2) * 72 + d];
        unsigned hi = PA[(qq * 16 + 2 * u2 + 1) * 72 + d];
        wds[u2] = lo | (hi << 16);
    }
    ushort_t* dst = PT + ((long)b * 64 + d) * 1024 + h * 64 + qq * 16;
    uint4 p0; unsigned* q0 = (unsigned*)&p0;
    q0[0] = wds[0]; q0[1] = wds[1]; q0[2] = wds[2]; q0[3] = wds[3];
    uint4 p1; unsigned* q1 = (unsigned*)&p1;
    q1[0] = wds[4]; q1[1] = wds[5]; q1[2] = wds[6]; q1[3] = wds[7];
    *(uint4*)dst = p0;
    *(uint4*)(dst + 8) = p1;
}

// ---------------- launch ----------------

extern "C" void kernel_launch(void* const* d_in, const int* in_sizes, int n_in,
                              void* d_out, int out_size, void* d_ws, size_t ws_size,
                              hipStream_t stream)
{
    (void)in_sizes; (void)n_in; (void)out_size; (void)ws_size;
    const float* x   = (const float*)d_in[0];
    const float* wu  = (const float*)d_in[1];
    const float* wv  = (const float*)d_in[2];
    const float* wvb = (const float*)d_in[3];
    const float* hw  = (const float*)d_in[4];
    const float* cpw = (const float*)d_in[5];
    const float* cpb = (const float*)d_in[6];
    float* out = (float*)d_out;

    char* ws = (char*)d_ws;
    ushort_t* x_bf    = (ushort_t*)(ws);                   // 32 MB  [16384][1024]
    ushort_t* xT_bf   = (ushort_t*)(ws + 33554432L);       // 32 MB  [8][1024][2048]
    ushort_t* XtX     = (ushort_t*)(ws + 67108864L);       // 16 MB  [8][1024][1024]
    ushort_t* W2      = (ushort_t*)(ws + 83886080L);       // 16 MB  [8][1024][1024]
    ushort_t* wu_bf   = (ushort_t*)(ws + 100663296L);      // 2 MB
    ushort_t* wv_bf   = (ushort_t*)(ws + 102760448L);      // 2 MB
    ushort_t* cproj   = (ushort_t*)(ws + 104857600L);      // 2 MB
    ushort_t* helperT = (ushort_t*)(ws + 106954752L);      // 128 KB
    float*    Sp      = (float*)   (ws + 107085824L);      // 2 MB   [8][16][64][64]
    float*    su      = (float*)   (ws + 109182976L);      // 32 KB
    float*    xsum    = (float*)   (ws + 109215744L);      // 32 KB
    ushort_t* PT      = (ushort_t*)(ws + 109248512L);      // 1 MB   [8][64][1024]
    ushort_t* GT      = (ushort_t*)(ws + 110297088L);      // 2 MB   [64][16384]
    ushort_t* Q       = (ushort_t*)(ws + 112394240L);      // 2 MB   [16][1024][64]

    // P0: x -> x_bf + xT_bf
    {
        dim3 g(32, 16, 8);
        k_trans<<<g, 256, 0, stream>>>(x, x_bf, xT_bf);
    }
    // weight preps
    k_conv_f32_bf16<<<2048, 256, 0, stream>>>(wu, wu_bf, 1048576);
    k_conv_f32_bf16<<<2048, 256, 0, stream>>>(wv, wv_bf, 1048576);
    k_conv_f32_bf16<<<2048, 256, 0, stream>>>(cpw, cproj, 1048576);
    k_prep_helperT <<<256, 256, 0, stream>>>(hw, helperT);

    // xsum, s_u
    {
        dim3 g(256, 8);
        k_xsum<<<g, 256, 0, stream>>>(xT_bf, xsum);
        k_su<<<g, 256, 0, stream>>>(wu_bf, xsum, su);
    }
    // XtX[b] = xT[b] @ xT[b]^T (upper-tri + mirror)
    {
        dim3 g(36, 1, 8);
        k_syrk<<<g, 256, 0, stream>>>(xT_bf, XtX);
    }
    // W2[b] = wu @ XtX[b]  (Bt = XtX by symmetry)
    {
        dim3 g(8, 8, 8);
        k_gemm_bt<0><<<g, 256, 0, stream>>>(wu_bf, XtX, W2, nullptr,
                                            1024, 1024, 1024, 1024, 0, 1048576L, 1048576L);
    }
    // S[b,h] = W2[b][h-rows] @ wv[h-rows]^T
    {
        dim3 g(16, 8);
        k_attn_s2<<<g, 256, 0, stream>>>(W2, wv_bf, Sp);
    }
    // softmax (+ s_u x b_v) -> PT
    {
        dim3 g(16, 8);
        k_attn_f<<<g, 256, 0, stream>>>(Sp, su, wvb, PT);
    }
    // G = x @ PstackT -> GT
    {
        dim3 g(128, 1, 1);
        k_skinny<0><<<g, 256, 0, stream>>>(x_bf, PT, GT);
    }
    // Q[z] = cproj @ G-part
    {
        dim3 g(8, 1, 16);
        k_skinny<1><<<g, 256, 0, stream>>>(cproj, GT, Q);
    }
    // out[b][2c+p][o] = helperT[c][:] . Q[z][o][:] + cpb[o]
    {
        dim3 g(8, 8, 16);
        k_gemm_bt<3><<<g, 256, 0, stream>>>(helperT, Q, (void*)out, cpb,
                                            64, 64, 64, 0, 0, 65536L, 0);
    }
}

// Round 5
// 184.109 us; speedup vs baseline: 1.7482x; 1.1434x over previous
//
#include <hip/hip_runtime.h>

typedef unsigned short ushort_t;
typedef __bf16 bf16x8 __attribute__((ext_vector_type(8)));
typedef float f32x4 __attribute__((ext_vector_type(4)));

__device__ __forceinline__ ushort_t f2bf(float f) {
    unsigned u = __builtin_bit_cast(unsigned, f);
    unsigned r = (u + 0x7fffu + ((u >> 16) & 1u)) >> 16;
    return (ushort_t)r;
}
__device__ __forceinline__ float bf2f(ushort_t u) {
    return __builtin_bit_cast(float, (unsigned)u << 16);
}

__device__ __forceinline__ void async16(const ushort_t* g, void* lds) {
    __builtin_amdgcn_global_load_lds(
        (const __attribute__((address_space(1))) void*)g,
        (__attribute__((address_space(3))) void*)lds, 16, 0, 0);
}

// ---------------- prep kernels ----------------

__global__ void k_zero(float4* __restrict__ p) {
    p[blockIdx.x * 256 + threadIdx.x] = float4{0.f, 0.f, 0.f, 0.f};
}

__global__ void k_conv_f32_bf16(const float* __restrict__ in, ushort_t* __restrict__ out, int n) {
    int i = blockIdx.x * blockDim.x + threadIdx.x;
    int st = gridDim.x * blockDim.x;
    for (; i < n; i += st) out[i] = f2bf(in[i]);
}

__global__ void k_prep_helperT(const float* __restrict__ hw, ushort_t* __restrict__ hT) {
    int i = blockIdx.x * blockDim.x + threadIdx.x;
    if (i < 65536) {
        int c = i >> 6, d = i & 63;
        hT[i] = f2bf(hw[d * 1024 + c]);   // helperT[c][d] = helper_w[d][c]
    }
}

// fused: x fp32 -> x_bf [16384][1024], xT_bf [8][1024][2048], xsum[b][c] += col-partials
__global__ __launch_bounds__(256)
void k_trans(const float* __restrict__ x, ushort_t* __restrict__ xbf,
             ushort_t* __restrict__ xT, float* __restrict__ xsum)
{
    __shared__ ushort_t T[64 * 72];
    const int t0 = blockIdx.x * 64, c0 = blockIdx.y * 64, b = blockIdx.z;
    const int tid = threadIdx.x;
    const int r = tid >> 2, q = tid & 3;
    #pragma unroll
    for (int i = 0; i < 4; ++i) {
        const int cq = q + i * 4;
        const long gi = ((long)(b * 2048 + t0 + r)) * 1024 + c0 + cq * 4;
        float4 f = *(const float4*)&x[gi];
        ushort4 o;
        o.x = f2bf(f.x); o.y = f2bf(f.y); o.z = f2bf(f.z); o.w = f2bf(f.w);
        *(ushort4*)&xbf[gi] = o;
        *(ushort4*)&T[r * 72 + cq * 4] = o;
    }
    __syncthreads();
    const int cl = tid >> 2, tq = tid & 3;
    float cs = 0.0f;
    #pragma unroll
    for (int i = 0; i < 4; ++i) {
        const int tc = tq + i * 4;
        ushort4 o;
        o.x = T[(tc * 4 + 0) * 72 + cl];
        o.y = T[(tc * 4 + 1) * 72 + cl];
        o.z = T[(tc * 4 + 2) * 72 + cl];
        o.w = T[(tc * 4 + 3) * 72 + cl];
        cs += bf2f(o.x) + bf2f(o.y) + bf2f(o.z) + bf2f(o.w);
        *(ushort4*)&xT[((long)(b * 1024 + c0 + cl)) * 2048 + t0 + tc * 4] = o;
    }
    cs += __shfl_xor(cs, 1, 64);
    cs += __shfl_xor(cs, 2, 64);
    if (tq == 0) atomicAdd(&xsum[b * 1024 + c0 + cl], cs);
}

// s_u[b][hs] = dot(w_u[hs,:], xsum[b,:])
__global__ __launch_bounds__(256)
void k_su(const ushort_t* __restrict__ wu, const float* __restrict__ xsum,
          float* __restrict__ su)
{
    const int tid = threadIdx.x, w = tid >> 6, lane = tid & 63;
    const int b = blockIdx.y, hs = blockIdx.x * 4 + w;
    const ushort_t* pw = wu + (long)hs * 1024 + lane * 16;
    const float* px = xsum + b * 1024 + lane * 16;
    float s = 0.0f;
    #pragma unroll
    for (int i = 0; i < 2; ++i) {
        bf16x8 a = *(const bf16x8*)(pw + i * 8);
        float4 f0 = *(const float4*)(px + i * 8);
        float4 f1 = *(const float4*)(px + i * 8 + 4);
        s += (float)a[0] * f0.x + (float)a[1] * f0.y + (float)a[2] * f0.z + (float)a[3] * f0.w
           + (float)a[4] * f1.x + (float)a[5] * f1.y + (float)a[6] * f1.z + (float)a[7] * f1.w;
    }
    #pragma unroll
    for (int o = 1; o < 64; o <<= 1) s += __shfl_xor(s, o, 64);
    if (lane == 0) su[b * 1024 + hs] = s;
}

// ---------------- generic GEMM: C[m,n] = sum_k A[m,k] * Bt[n,k] (+bias[n]) ----------------
// 128x128 tile, BK=64, XOR-swizzled LDS, 4 waves.
// OUT_MODE: 0 = bf16 row-major, 3 = f32 interleaved out[(z>>1)*2048 + 2*row + (z&1)][col]
// SWZ: 1 -> 1D grid, z = id&7 (XCD affinity), bx = (id>>3)&7, by = id>>6

template<int OUT_MODE, int SWZ>
__global__ __launch_bounds__(256)
void k_gemm_bt(const ushort_t* __restrict__ A, const ushort_t* __restrict__ Bt,
               void* __restrict__ Cv, const float* __restrict__ bias,
               int K, int ldA, int ldB, int ldC,
               long sA, long sB, long sC)
{
    __shared__ ushort_t smem[16896];
    ushort_t* As = smem;
    ushort_t* Bs = smem + 8192;
    int z, bx, by;
    if (SWZ) { z = blockIdx.x & 7; int t = blockIdx.x >> 3; bx = t & 7; by = t >> 3; }
    else     { z = blockIdx.z; bx = blockIdx.x; by = blockIdx.y; }
    const ushort_t* Ab = A + (long)z * sA;
    const ushort_t* Bb = Bt + (long)z * sB;
    const int m0 = bx * 128;
    const int n0 = by * 128;
    const int tid = threadIdx.x;
    const int w = tid >> 6;
    const int lane = tid & 63;
    const int l15 = lane & 15, l4 = lane >> 4;
    const int wr = (w >> 1) * 64, wc = (w & 1) * 64;

    f32x4 acc[4][4] = {};
    const int srow = lane >> 3;
    const int gchunk = (lane & 7) ^ srow;

    for (int kt = 0; kt < K; kt += 64) {
        __syncthreads();
        #pragma unroll
        for (int q = 0; q < 4; ++q) {
            const int seg = w * 4 + q;
            const int r = seg * 8 + srow;
            async16(Ab + (long)(m0 + r) * ldA + kt + gchunk * 8, (char*)As + seg * 1024);
            async16(Bb + (long)(n0 + r) * ldB + kt + gchunk * 8, (char*)Bs + seg * 1024);
        }
        __syncthreads();
        #pragma unroll
        for (int kk = 0; kk < 2; ++kk) {
            bf16x8 af[4], bfr[4];
            const int swz = ((kk * 4 + l4) ^ (l15 & 7)) * 8;
            #pragma unroll
            for (int i = 0; i < 4; ++i) {
                af[i]  = *(const bf16x8*)&As[(wr + i * 16 + l15) * 64 + swz];
                bfr[i] = *(const bf16x8*)&Bs[(wc + i * 16 + l15) * 64 + swz];
            }
            #pragma unroll
            for (int i = 0; i < 4; ++i)
                #pragma unroll
                for (int j = 0; j < 4; ++j)
                    acc[i][j] = __builtin_amdgcn_mfma_f32_16x16x32_bf16(af[i], bfr[j], acc[i][j], 0, 0, 0);
        }
    }

    if (OUT_MODE == 3) {
        const int bb_ = z >> 1, pp_ = z & 1;
        float* O = (float*)Cv + (long)bb_ * 2097152 + (long)pp_ * 1024;
        #pragma unroll
        for (int i = 0; i < 4; ++i) {
            #pragma unroll
            for (int j = 0; j < 4; ++j) {
                const int row0 = m0 + wr + i * 16 + l4 * 4;
                const int col  = n0 + wc + j * 16 + l15;
                const float bv = bias[col];
                #pragma unroll
                for (int e = 0; e < 4; ++e)
                    O[(long)(row0 + e) * 2048 + col] = acc[i][j][e] + bv;
            }
        }
    } else {
        #pragma unroll
        for (int i = 0; i < 4; ++i) {
            #pragma unroll
            for (int j = 0; j < 4; ++j) {
                const int row0 = m0 + wr + i * 16 + l4 * 4;
                const int col  = n0 + wc + j * 16 + l15;
                const float bv = bias ? bias[col] : 0.0f;
                #pragma unroll
                for (int e = 0; e < 4; ++e)
                    ((ushort_t*)Cv)[(long)z * sC + (long)(row0 + e) * ldC + col] = f2bf(acc[i][j][e] + bv);
            }
        }
    }
}

// ---------------- SYRK: XtX[b] = xT[b] @ xT[b]^T, 128x64 upper tiles + mirror, XCD-affine ----------------
// grid 576 = 8 b x 72 tiles; b = id&7 so XCD k keeps xT[k] (4 MB) in its L2.

__global__ __launch_bounds__(256)
void k_syrk(const ushort_t* __restrict__ xT, ushort_t* __restrict__ XtX)
{
    __shared__ ushort_t smem[12288];     // As [128][64] + Bs [64][64]; epilogue reuses [128][66]
    ushort_t* As = smem;
    ushort_t* Bs = smem + 8192;
    const int id = blockIdx.x;
    const int z = id & 7;
    int L = id >> 3, bi = 0;
    while (L >= 16 - 2 * bi) { L -= 16 - 2 * bi; ++bi; }
    const int cj = 2 * bi + L;           // col-tile (64 wide), cj >= 2*bi
    const ushort_t* base = xT + (long)z * 2097152;   // [1024][2048]
    const ushort_t* Ab = base + (long)bi * 128 * 2048;
    const ushort_t* Bb = base + (long)cj * 64 * 2048;
    ushort_t* C = XtX + (long)z * 1048576;           // [1024][1024]
    const int tid = threadIdx.x;
    const int w = tid >> 6;
    const int lane = tid & 63;
    const int l15 = lane & 15, l4 = lane >> 4;
    const int wr = (w >> 1) * 64, wc = (w & 1) * 32;

    f32x4 acc[4][2] = {};
    const int srow = lane >> 3;
    const int gchunk = (lane & 7) ^ srow;

    for (int kt = 0; kt < 2048; kt += 64) {
        __syncthreads();
        #pragma unroll
        for (int q = 0; q < 4; ++q) {
            const int seg = w * 4 + q;               // 0..15
            async16(Ab + (long)(seg * 8 + srow) * 2048 + kt + gchunk * 8, (char*)As + seg * 1024);
        }
        #pragma unroll
        for (int q = 0; q < 2; ++q) {
            const int seg = w * 2 + q;               // 0..7
            async16(Bb + (long)(seg * 8 + srow) * 2048 + kt + gchunk * 8, (char*)Bs + seg * 1024);
        }
        __syncthreads();
        #pragma unroll
        for (int kk = 0; kk < 2; ++kk) {
            bf16x8 af[4], bfr[2];
            const int swz = ((kk * 4 + l4) ^ (l15 & 7)) * 8;
            #pragma unroll
            for (int i = 0; i < 4; ++i)
                af[i] = *(const bf16x8*)&As[(wr + i * 16 + l15) * 64 + swz];
            #pragma unroll
            for (int nf = 0; nf < 2; ++nf)
                bfr[nf] = *(const bf16x8*)&Bs[(wc + nf * 16 + l15) * 64 + swz];
            #pragma unroll
            for (int i = 0; i < 4; ++i)
                #pragma unroll
                for (int nf = 0; nf < 2; ++nf)
                    acc[i][nf] = __builtin_amdgcn_mfma_f32_16x16x32_bf16(af[i], bfr[nf], acc[i][nf], 0, 0, 0);
        }
    }

    // normal write at (bi*128 + m, cj*64 + n)
    #pragma unroll
    for (int i = 0; i < 4; ++i) {
        #pragma unroll
        for (int nf = 0; nf < 2; ++nf) {
            const int row0 = bi * 128 + wr + i * 16 + l4 * 4;
            const int col  = cj * 64 + wc + nf * 16 + l15;
            #pragma unroll
            for (int e = 0; e < 4; ++e)
                C[(long)(row0 + e) * 1024 + col] = f2bf(acc[i][nf][e]);
        }
    }
    // mirror write (diag-crossing overlap writes identical values -> benign)
    __syncthreads();
    #pragma unroll
    for (int i = 0; i < 4; ++i)
        #pragma unroll
        for (int nf = 0; nf < 2; ++nf)
            #pragma unroll
            for (int e = 0; e < 4; ++e)
                smem[(wr + i * 16 + l4 * 4 + e) * 66 + wc + nf * 16 + l15] = f2bf(acc[i][nf][e]);
    __syncthreads();
    const int nr = tid & 63;       // local n (row of mirror)
    const int mh = tid >> 6;       // m quarter (32 each)
    unsigned wds[16];
    #pragma unroll
    for (int u = 0; u < 16; ++u) {
        const int m = mh * 32 + u * 2;
        unsigned lo = smem[m * 66 + nr];
        unsigned hi = smem[(m + 1) * 66 + nr];
        wds[u] = lo | (hi << 16);
    }
    #pragma unroll
    for (int v = 0; v < 4; ++v) {
        uint4 pk; unsigned* pw = (unsigned*)&pk;
        pw[0] = wds[v * 4]; pw[1] = wds[v * 4 + 1]; pw[2] = wds[v * 4 + 2]; pw[3] = wds[v * 4 + 3];
        *(uint4*)&C[(long)(cj * 64 + nr) * 1024 + bi * 128 + mh * 32 + v * 8] = pk;
    }
}

// ---------------- skinny GEMM: 64(M) x 64(N) tile, K=1024, Bt rows from global ----------------
// MODE 0: G = x @ PT[b]^T -> GT[64][16384] (transposed out); grid 256, b = id&7
// MODE 1: Q[z] = cproj @ G-part  -> Q[z][o][d]; grid 256, z = id&15

template<int MODE>
__global__ __launch_bounds__(256)
void k_skinny(const ushort_t* __restrict__ A, const ushort_t* __restrict__ Bt,
              ushort_t* __restrict__ C)
{
    __shared__ ushort_t smem[4224];      // As [64][64]=4096; MODE0 epilogue [64][66]=4224
    ushort_t* As = smem;
    const int id = blockIdx.x;
    const int tid = threadIdx.x;
    const int w = tid >> 6, lane = tid & 63;
    const int l15 = lane & 15, l4 = lane >> 4;

    int m0, z;
    if (MODE == 0) { const int b = id & 7, tl = id >> 3; m0 = (b * 32 + tl) * 64; z = b; }
    else           { z = id & 15; m0 = (id >> 4) * 64; }

    const ushort_t* Ab = A + (long)m0 * 1024;
    const ushort_t* Bb; int ldB;
    if (MODE == 0) { Bb = Bt + (long)z * 65536; ldB = 1024; }
    else           { Bb = Bt + (long)z * 1024;  ldB = 16384; }

    const int wr = (w >> 1) * 32, wc = (w & 1) * 32;
    f32x4 acc[2][2] = {};
    const int srow = lane >> 3;
    const int gchunk = (lane & 7) ^ srow;

    for (int kt = 0; kt < 1024; kt += 64) {
        __syncthreads();
        #pragma unroll
        for (int q = 0; q < 2; ++q) {
            const int seg = w * 2 + q;               // 0..7
            async16(Ab + (long)(seg * 8 + srow) * 1024 + kt + gchunk * 8, (char*)As + seg * 1024);
        }
        __syncthreads();
        #pragma unroll
        for (int kk = 0; kk < 2; ++kk) {
            const int swz = ((kk * 4 + l4) ^ (l15 & 7)) * 8;
            bf16x8 af[2], bfr[2];
            #pragma unroll
            for (int i = 0; i < 2; ++i)
                af[i] = *(const bf16x8*)&As[(wr + i * 16 + l15) * 64 + swz];
            #pragma unroll
            for (int nf = 0; nf < 2; ++nf)
                bfr[nf] = *(const bf16x8*)&Bb[(long)(wc + nf * 16 + l15) * ldB + kt + kk * 32 + l4 * 8];
            #pragma unroll
            for (int i = 0; i < 2; ++i)
                #pragma unroll
                for (int nf = 0; nf < 2; ++nf)
                    acc[i][nf] = __builtin_amdgcn_mfma_f32_16x16x32_bf16(af[i], bfr[nf], acc[i][nf], 0, 0, 0);
        }
    }

    if (MODE == 0) {
        __syncthreads();
        #pragma unroll
        for (int i = 0; i < 2; ++i)
            #pragma unroll
            for (int nf = 0; nf < 2; ++nf)
                #pragma unroll
                for (int e = 0; e < 4; ++e)
                    smem[(wr + i * 16 + l4 * 4 + e) * 66 + wc + nf * 16 + l15] = f2bf(acc[i][nf][e]);
        __syncthreads();
        const int d = tid >> 2, qq = tid & 3;        // row d of GT, m-chunk qq*16
        unsigned wds[8];
        #pragma unroll
        for (int u = 0; u < 8; ++u) {
            const int m = qq * 16 + u * 2;
            unsigned lo = smem[m * 66 + d];
            unsigned hi = smem[(m + 1) * 66 + d];
            wds[u] = lo | (hi << 16);
        }
        uint4 p0; unsigned* q0 = (unsigned*)&p0;
        q0[0] = wds[0]; q0[1] = wds[1]; q0[2] = wds[2]; q0[3] = wds[3];
        uint4 p1; unsigned* q1 = (unsigned*)&p1;
        q1[0] = wds[4]; q1[1] = wds[5]; q1[2] = wds[6]; q1[3] = wds[7];
        *(uint4*)&C[(long)d * 16384 + m0 + qq * 16] = p0;
        *(uint4*)&C[(long)d * 16384 + m0 + qq * 16 + 8] = p1;
    } else {
        ushort_t* Co = C + (long)z * 65536;
        #pragma unroll
        for (int i = 0; i < 2; ++i)
            #pragma unroll
            for (int nf = 0; nf < 2; ++nf)
                #pragma unroll
                for (int e = 0; e < 4; ++e)
                    Co[(long)(m0 + wr + i * 16 + l4 * 4 + e) * 64 + wc + nf * 16 + l15] = f2bf(acc[i][nf][e]);
    }
}

// ---------------- fused S-GEMM + softmax -> PstackT ----------------
// grid 128: b = id&7 (XCD affinity: W2[b] 2MB + wv 2MB in L2), h = id>>3
// S = W2[b][h-rows] @ wv[h-rows]^T (+ su x wvb), causal softmax, PT[b][d][h*64+s] = P[s][d]

__global__ __launch_bounds__(256)
void k_attn2(const ushort_t* __restrict__ W2, const ushort_t* __restrict__ wv,
             const float* __restrict__ su, const float* __restrict__ wvb,
             ushort_t* __restrict__ PT)
{
    __shared__ ushort_t PA[64 * 72];
    const int b = blockIdx.x & 7, h = blockIdx.x >> 3;
    const int tid = threadIdx.x;
    const int w = tid >> 6, lane = tid & 63;
    const int l15 = lane & 15, l4 = lane >> 4;

    f32x4 sf[4] = {};
    const ushort_t* pa  = W2 + (long)b * 1048576 + (long)(h * 64 + w * 16 + l15) * 1024 + l4 * 8;
    const ushort_t* pb0 = wv + (long)(h * 64 + l15) * 1024 + l4 * 8;

    #pragma unroll 2
    for (int kt = 0; kt < 1024; kt += 32) {
        bf16x8 a = *(const bf16x8*)(pa + kt);
        #pragma unroll
        for (int nf = 0; nf < 4; ++nf) {
            bf16x8 bb = *(const bf16x8*)(pb0 + (long)(nf * 16) * 1024 + kt);
            sf[nf] = __builtin_amdgcn_mfma_f32_16x16x32_bf16(a, bb, sf[nf], 0, 0, 0);
        }
    }

    const float scale = 0.03125f;   // 1/sqrt(1024)
    const int rb = w * 16 + l4 * 4;
    #pragma unroll
    for (int j = 0; j < 4; ++j) {
        const int srowi = rb + j;
        const float suv = su[b * 1024 + h * 64 + srowi];
        float v[4];
        #pragma unroll
        for (int nf = 0; nf < 4; ++nf) {
            const int col = nf * 16 + l15;
            const float sv = sf[nf][j] + suv * wvb[h * 64 + col];
            v[nf] = (col <= srowi) ? sv * scale : -3.0e38f;
        }
        float mx = fmaxf(fmaxf(v[0], v[1]), fmaxf(v[2], v[3]));
        #pragma unroll
        for (int o = 1; o < 16; o <<= 1) mx = fmaxf(mx, __shfl_xor(mx, o, 64));
        float s = 0.0f;
        #pragma unroll
        for (int nf = 0; nf < 4; ++nf) { v[nf] = __expf(v[nf] - mx); s += v[nf]; }
        #pragma unroll
        for (int o = 1; o < 16; o <<= 1) s += __shfl_xor(s, o, 64);
        const float inv = 1.0f / s;
        #pragma unroll
        for (int nf = 0; nf < 4; ++nf)
            PA[srowi * 72 + nf * 16 + l15] = f2bf(v[nf] * inv);
    }
    __syncthreads();

    const int d = tid >> 2, qq = tid & 3;
    unsigned wds[8];
    #pragma unroll
    for (int u2 = 0; u2 < 8; ++u2) {
        unsigned lo = PA[(qq * 16 + 2 * u2) * 72 + d];
        unsigned hi = PA[(qq * 16 + 2 * u2 + 1) * 72 + d];
        wds[u2] = lo | (hi << 16);
    }
    ushort_t* dst = PT + ((long)b * 64 + d) * 1024 + h * 64 + qq * 16;
    uint4 p0; unsigned* q0 = (unsigned*)&p0;
    q0[0] = wds[0]; q0[1] = wds[1]; q0[2] = wds[2]; q0[3] = wds[3];
    uint4 p1; unsigned* q1 = (unsigned*)&p1;
    q1[0] = wds[4]; q1[1] = wds[5]; q1[2] = wds[6]; q1[3] = wds[7];
    *(uint4*)dst = p0;
    *(uint4*)(dst + 8) = p1;
}

// ---------------- launch ----------------

extern "C" void kernel_launch(void* const* d_in, const int* in_sizes, int n_in,
                              void* d_out, int out_size, void* d_ws, size_t ws_size,
                              hipStream_t stream)
{
    (void)in_sizes; (void)n_in; (void)out_size; (void)ws_size;
    const float* x   = (const float*)d_in[0];
    const float* wu  = (const float*)d_in[1];
    const float* wv  = (const float*)d_in[2];
    const float* wvb = (const float*)d_in[3];
    const float* hw  = (const float*)d_in[4];
    const float* cpw = (const float*)d_in[5];
    const float* cpb = (const float*)d_in[6];
    float* out = (float*)d_out;

    char* ws = (char*)d_ws;
    ushort_t* x_bf    = (ushort_t*)(ws);                   // 32 MB  [16384][1024]
    ushort_t* xT_bf   = (ushort_t*)(ws + 33554432L);       // 32 MB  [8][1024][2048]
    ushort_t* XtX     = (ushort_t*)(ws + 67108864L);       // 16 MB  [8][1024][1024]
    ushort_t* W2      = (ushort_t*)(ws + 83886080L);       // 16 MB  [8][1024][1024]
    ushort_t* wu_bf   = (ushort_t*)(ws + 100663296L);      // 2 MB
    ushort_t* wv_bf   = (ushort_t*)(ws + 102760448L);      // 2 MB
    ushort_t* cproj   = (ushort_t*)(ws + 104857600L);      // 2 MB
    ushort_t* helperT = (ushort_t*)(ws + 106954752L);      // 128 KB [1024][64]
    ushort_t* PT      = (ushort_t*)(ws + 107085824L);      // 1 MB   [8][64][1024]
    ushort_t* GT      = (ushort_t*)(ws + 108134400L);      // 2 MB   [64][16384]
    ushort_t* Q       = (ushort_t*)(ws + 110231552L);      // 2 MB   [16][1024][64]
    float*    xsum    = (float*)   (ws + 112328704L);      // 32 KB  [8][1024]
    float*    su      = (float*)   (ws + 112361472L);      // 32 KB  [8][1024]

    // prep
    k_zero<<<8, 256, 0, stream>>>((float4*)xsum);
    {
        dim3 g(32, 16, 8);
        k_trans<<<g, 256, 0, stream>>>(x, x_bf, xT_bf, xsum);
    }
    k_conv_f32_bf16<<<2048, 256, 0, stream>>>(wu, wu_bf, 1048576);
    k_conv_f32_bf16<<<2048, 256, 0, stream>>>(wv, wv_bf, 1048576);
    k_conv_f32_bf16<<<2048, 256, 0, stream>>>(cpw, cproj, 1048576);
    k_prep_helperT <<<256, 256, 0, stream>>>(hw, helperT);
    {
        dim3 g(256, 8);
        k_su<<<g, 256, 0, stream>>>(wu_bf, xsum, su);
    }

    // XtX[b] = xT[b] @ xT[b]^T  (576 blocks, XCD-affine)
    k_syrk<<<576, 256, 0, stream>>>(xT_bf, XtX);

    // W2[b] = wu @ XtX[b]  (Bt = XtX by symmetry; 512 blocks, XCD-affine)
    k_gemm_bt<0, 1><<<512, 256, 0, stream>>>(wu_bf, XtX, W2, nullptr,
                                             1024, 1024, 1024, 1024, 0, 1048576L, 1048576L);

    // fused S + softmax -> PT
    k_attn2<<<128, 256, 0, stream>>>(W2, wv_bf, su, wvb, PT);

    // G = x @ PstackT -> GT
    k_skinny<0><<<256, 256, 0, stream>>>(x_bf, PT, GT);

    // Q[z] = cproj @ G-part
    k_skinny<1><<<256, 256, 0, stream>>>(cproj, GT, Q);

    // out[b][2c+p][o] = helperT[c][:] . Q[z][o][:] + cpb[o]
    {
        dim3 g(8, 8, 16);
        k_gemm_bt<3, 0><<<g, 256, 0, stream>>>(helperT, Q, (void*)out, cpb,
                                               64, 64, 64, 0, 0, 65536L, 0);
    }
}

// Round 6
// 167.649 us; speedup vs baseline: 1.9198x; 1.0982x over previous
//
#include <hip/hip_runtime.h>

typedef unsigned short ushort_t;
typedef __bf16 bf16x8 __attribute__((ext_vector_type(8)));
typedef float f32x4 __attribute__((ext_vector_type(4)));

__device__ __forceinline__ ushort_t f2bf(float f) {
    unsigned u = __builtin_bit_cast(unsigned, f);
    unsigned r = (u + 0x7fffu + ((u >> 16) & 1u)) >> 16;
    return (ushort_t)r;
}
__device__ __forceinline__ float bf2f(ushort_t u) {
    return __builtin_bit_cast(float, (unsigned)u << 16);
}

__device__ __forceinline__ void async16(const ushort_t* g, void* lds) {
    __builtin_amdgcn_global_load_lds(
        (const __attribute__((address_space(1))) void*)g,
        (__attribute__((address_space(3))) void*)lds, 16, 0, 0);
}

// ---------------- merged prep: zero xsum + bf16-convert all weights + helperT ----------------

__global__ __launch_bounds__(256)
void k_prep(const float* __restrict__ wu, const float* __restrict__ wv,
            const float* __restrict__ cpw, const float* __restrict__ hw,
            ushort_t* __restrict__ wu_bf, ushort_t* __restrict__ wv_bf,
            ushort_t* __restrict__ cproj, ushort_t* __restrict__ hT,
            float* __restrict__ xsum)
{
    const int gid = blockIdx.x * 256 + threadIdx.x;
    if (gid < 8192) xsum[gid] = 0.0f;
    const int st = gridDim.x * 256;
    for (int i = gid; i < 1048576; i += st) {
        wu_bf[i] = f2bf(wu[i]);
        wv_bf[i] = f2bf(wv[i]);
        cproj[i] = f2bf(cpw[i]);
        if (i < 65536) {
            int c = i >> 6, d = i & 63;
            hT[i] = f2bf(hw[d * 1024 + c]);   // helperT[c][d] = helper_w[d][c]
        }
    }
}

// fused: x fp32 -> x_bf [16384][1024], xT_bf [8][1024][2048], xsum[b][c] += col-partials
__global__ __launch_bounds__(256)
void k_trans(const float* __restrict__ x, ushort_t* __restrict__ xbf,
             ushort_t* __restrict__ xT, float* __restrict__ xsum)
{
    __shared__ ushort_t T[64 * 72];
    const int t0 = blockIdx.x * 64, c0 = blockIdx.y * 64, b = blockIdx.z;
    const int tid = threadIdx.x;
    const int r = tid >> 2, q = tid & 3;
    #pragma unroll
    for (int i = 0; i < 4; ++i) {
        const int cq = q + i * 4;
        const long gi = ((long)(b * 2048 + t0 + r)) * 1024 + c0 + cq * 4;
        float4 f = *(const float4*)&x[gi];
        ushort4 o;
        o.x = f2bf(f.x); o.y = f2bf(f.y); o.z = f2bf(f.z); o.w = f2bf(f.w);
        *(ushort4*)&xbf[gi] = o;
        *(ushort4*)&T[r * 72 + cq * 4] = o;
    }
    __syncthreads();
    const int cl = tid >> 2, tq = tid & 3;
    float cs = 0.0f;
    #pragma unroll
    for (int i = 0; i < 4; ++i) {
        const int tc = tq + i * 4;
        ushort4 o;
        o.x = T[(tc * 4 + 0) * 72 + cl];
        o.y = T[(tc * 4 + 1) * 72 + cl];
        o.z = T[(tc * 4 + 2) * 72 + cl];
        o.w = T[(tc * 4 + 3) * 72 + cl];
        cs += bf2f(o.x) + bf2f(o.y) + bf2f(o.z) + bf2f(o.w);
        *(ushort4*)&xT[((long)(b * 1024 + c0 + cl)) * 2048 + t0 + tc * 4] = o;
    }
    cs += __shfl_xor(cs, 1, 64);
    cs += __shfl_xor(cs, 2, 64);
    if (tq == 0) atomicAdd(&xsum[b * 1024 + c0 + cl], cs);
}

// ---------------- generic GEMM: C[m,n] = sum_k A[m,k] * Bt[n,k] (+bias[n]) ----------------
// 128x128 tile, BK=64, XOR-swizzled LDS, double-buffered 2-phase, 4 waves.
// OUT_MODE: 0 = bf16 row-major, 3 = f32 interleaved out[(z>>1)*2048 + 2*row + (z&1)][col]
// SWZ: 1 -> 1D grid, z = id&7 (XCD affinity), bx = (id>>3)&7, by = id>>6

template<int OUT_MODE, int SWZ>
__global__ __launch_bounds__(256)
void k_gemm_bt(const ushort_t* __restrict__ A, const ushort_t* __restrict__ Bt,
               void* __restrict__ Cv, const float* __restrict__ bias,
               int K, int ldA, int ldB, int ldC,
               long sA, long sB, long sC)
{
    __shared__ ushort_t smem[32768];     // As[2][8192] @0, Bs[2][8192] @16384
    int z, bx, by;
    if (SWZ) { z = blockIdx.x & 7; int t = blockIdx.x >> 3; bx = t & 7; by = t >> 3; }
    else     { z = blockIdx.z; bx = blockIdx.x; by = blockIdx.y; }
    const ushort_t* Ab = A + (long)z * sA;
    const ushort_t* Bb = Bt + (long)z * sB;
    const int m0 = bx * 128;
    const int n0 = by * 128;
    const int tid = threadIdx.x;
    const int w = tid >> 6;
    const int lane = tid & 63;
    const int l15 = lane & 15, l4 = lane >> 4;
    const int wr = (w >> 1) * 64, wc = (w & 1) * 64;

    f32x4 acc[4][4] = {};
    const int srow = lane >> 3;
    const int gchunk = (lane & 7) ^ srow;

    // prologue stage into buf 0
    #pragma unroll
    for (int q = 0; q < 4; ++q) {
        const int seg = w * 4 + q;
        const int r = seg * 8 + srow;
        async16(Ab + (long)(m0 + r) * ldA + gchunk * 8, (char*)smem + seg * 1024);
        async16(Bb + (long)(n0 + r) * ldB + gchunk * 8, (char*)smem + 32768 + seg * 1024);
    }
    __syncthreads();

    int cur = 0;
    for (int kt = 0; kt < K; kt += 64) {
        if (kt + 64 < K) {
            const int nb = cur ^ 1;
            #pragma unroll
            for (int q = 0; q < 4; ++q) {
                const int seg = w * 4 + q;
                const int r = seg * 8 + srow;
                async16(Ab + (long)(m0 + r) * ldA + kt + 64 + gchunk * 8,
                        (char*)smem + nb * 16384 + seg * 1024);
                async16(Bb + (long)(n0 + r) * ldB + kt + 64 + gchunk * 8,
                        (char*)smem + 32768 + nb * 16384 + seg * 1024);
            }
        }
        const ushort_t* Acur = smem + cur * 8192;
        const ushort_t* Bcur = smem + 16384 + cur * 8192;
        #pragma unroll
        for (int kk = 0; kk < 2; ++kk) {
            bf16x8 af[4], bfr[4];
            const int swz = ((kk * 4 + l4) ^ (l15 & 7)) * 8;
            #pragma unroll
            for (int i = 0; i < 4; ++i) {
                af[i]  = *(const bf16x8*)&Acur[(wr + i * 16 + l15) * 64 + swz];
                bfr[i] = *(const bf16x8*)&Bcur[(wc + i * 16 + l15) * 64 + swz];
            }
            __builtin_amdgcn_s_setprio(1);
            #pragma unroll
            for (int i = 0; i < 4; ++i)
                #pragma unroll
                for (int j = 0; j < 4; ++j)
                    acc[i][j] = __builtin_amdgcn_mfma_f32_16x16x32_bf16(af[i], bfr[j], acc[i][j], 0, 0, 0);
            __builtin_amdgcn_s_setprio(0);
        }
        __syncthreads();
        cur ^= 1;
    }

    if (OUT_MODE == 3) {
        const int bb_ = z >> 1, pp_ = z & 1;
        float* O = (float*)Cv + (long)bb_ * 2097152 + (long)pp_ * 1024;
        #pragma unroll
        for (int i = 0; i < 4; ++i) {
            #pragma unroll
            for (int j = 0; j < 4; ++j) {
                const int row0 = m0 + wr + i * 16 + l4 * 4;
                const int col  = n0 + wc + j * 16 + l15;
                const float bv = bias[col];
                #pragma unroll
                for (int e = 0; e < 4; ++e)
                    O[(long)(row0 + e) * 2048 + col] = acc[i][j][e] + bv;
            }
        }
    } else {
        #pragma unroll
        for (int i = 0; i < 4; ++i) {
            #pragma unroll
            for (int j = 0; j < 4; ++j) {
                const int row0 = m0 + wr + i * 16 + l4 * 4;
                const int col  = n0 + wc + j * 16 + l15;
                const float bv = bias ? bias[col] : 0.0f;
                #pragma unroll
                for (int e = 0; e < 4; ++e)
                    ((ushort_t*)Cv)[(long)z * sC + (long)(row0 + e) * ldC + col] = f2bf(acc[i][j][e] + bv);
            }
        }
    }
}

// ---------------- SYRK: XtX[b] = xT[b] @ xT[b]^T, 128x64 upper tiles + mirror, XCD-affine ----------------
// grid 576 = 8 b x 72 tiles; b = id&7. Double-buffered 2-phase.

__global__ __launch_bounds__(256)
void k_syrk(const ushort_t* __restrict__ xT, ushort_t* __restrict__ XtX)
{
    __shared__ ushort_t smem[24576];     // As[2][8192] @0, Bs[2][4096] @16384; epilogue reuses [0..8448)
    const int id = blockIdx.x;
    const int z = id & 7;
    int L = id >> 3, bi = 0;
    while (L >= 16 - 2 * bi) { L -= 16 - 2 * bi; ++bi; }
    const int cj = 2 * bi + L;           // col-tile (64 wide), cj >= 2*bi
    const ushort_t* base = xT + (long)z * 2097152;   // [1024][2048]
    const ushort_t* Ab = base + (long)bi * 128 * 2048;
    const ushort_t* Bb = base + (long)cj * 64 * 2048;
    ushort_t* C = XtX + (long)z * 1048576;           // [1024][1024]
    const int tid = threadIdx.x;
    const int w = tid >> 6;
    const int lane = tid & 63;
    const int l15 = lane & 15, l4 = lane >> 4;
    const int wr = (w >> 1) * 64, wc = (w & 1) * 32;

    f32x4 acc[4][2] = {};
    const int srow = lane >> 3;
    const int gchunk = (lane & 7) ^ srow;

    #pragma unroll
    for (int q = 0; q < 4; ++q) {
        const int seg = w * 4 + q;
        async16(Ab + (long)(seg * 8 + srow) * 2048 + gchunk * 8, (char*)smem + seg * 1024);
    }
    #pragma unroll
    for (int q = 0; q < 2; ++q) {
        const int seg = w * 2 + q;
        async16(Bb + (long)(seg * 8 + srow) * 2048 + gchunk * 8, (char*)smem + 32768 + seg * 1024);
    }
    __syncthreads();

    int cur = 0;
    for (int kt = 0; kt < 2048; kt += 64) {
        if (kt + 64 < 2048) {
            const int nb = cur ^ 1;
            #pragma unroll
            for (int q = 0; q < 4; ++q) {
                const int seg = w * 4 + q;
                async16(Ab + (long)(seg * 8 + srow) * 2048 + kt + 64 + gchunk * 8,
                        (char*)smem + nb * 16384 + seg * 1024);
            }
            #pragma unroll
            for (int q = 0; q < 2; ++q) {
                const int seg = w * 2 + q;
                async16(Bb + (long)(seg * 8 + srow) * 2048 + kt + 64 + gchunk * 8,
                        (char*)smem + 32768 + nb * 8192 + seg * 1024);
            }
        }
        const ushort_t* Acur = smem + cur * 8192;
        const ushort_t* Bcur = smem + 16384 + cur * 4096;
        #pragma unroll
        for (int kk = 0; kk < 2; ++kk) {
            bf16x8 af[4], bfr[2];
            const int swz = ((kk * 4 + l4) ^ (l15 & 7)) * 8;
            #pragma unroll
            for (int i = 0; i < 4; ++i)
                af[i] = *(const bf16x8*)&Acur[(wr + i * 16 + l15) * 64 + swz];
            #pragma unroll
            for (int nf = 0; nf < 2; ++nf)
                bfr[nf] = *(const bf16x8*)&Bcur[(wc + nf * 16 + l15) * 64 + swz];
            __builtin_amdgcn_s_setprio(1);
            #pragma unroll
            for (int i = 0; i < 4; ++i)
                #pragma unroll
                for (int nf = 0; nf < 2; ++nf)
                    acc[i][nf] = __builtin_amdgcn_mfma_f32_16x16x32_bf16(af[i], bfr[nf], acc[i][nf], 0, 0, 0);
            __builtin_amdgcn_s_setprio(0);
        }
        __syncthreads();
        cur ^= 1;
    }

    // normal write at (bi*128 + m, cj*64 + n)
    #pragma unroll
    for (int i = 0; i < 4; ++i) {
        #pragma unroll
        for (int nf = 0; nf < 2; ++nf) {
            const int row0 = bi * 128 + wr + i * 16 + l4 * 4;
            const int col  = cj * 64 + wc + nf * 16 + l15;
            #pragma unroll
            for (int e = 0; e < 4; ++e)
                C[(long)(row0 + e) * 1024 + col] = f2bf(acc[i][nf][e]);
        }
    }
    // mirror write (diag-crossing overlap writes identical values -> benign)
    __syncthreads();
    #pragma unroll
    for (int i = 0; i < 4; ++i)
        #pragma unroll
        for (int nf = 0; nf < 2; ++nf)
            #pragma unroll
            for (int e = 0; e < 4; ++e)
                smem[(wr + i * 16 + l4 * 4 + e) * 66 + wc + nf * 16 + l15] = f2bf(acc[i][nf][e]);
    __syncthreads();
    const int nr = tid & 63;
    const int mh = tid >> 6;
    unsigned wds[16];
    #pragma unroll
    for (int u = 0; u < 16; ++u) {
        const int m = mh * 32 + u * 2;
        unsigned lo = smem[m * 66 + nr];
        unsigned hi = smem[(m + 1) * 66 + nr];
        wds[u] = lo | (hi << 16);
    }
    #pragma unroll
    for (int v = 0; v < 4; ++v) {
        uint4 pk; unsigned* pw = (unsigned*)&pk;
        pw[0] = wds[v * 4]; pw[1] = wds[v * 4 + 1]; pw[2] = wds[v * 4 + 2]; pw[3] = wds[v * 4 + 3];
        *(uint4*)&C[(long)(cj * 64 + nr) * 1024 + bi * 128 + mh * 32 + v * 8] = pk;
    }
}

// ---------------- skinny GEMM: 64(M) x 64(N) tile, K=1024, Bt rows from global, dbuf ----------------
// MODE 0: G = x @ PT[b]^T -> GT[64][16384] (transposed out); grid 256, b = id&7
// MODE 1: Q[z] = cproj @ G-part  -> Q[z][o][d]; grid 256, z = id&15

template<int MODE>
__global__ __launch_bounds__(256)
void k_skinny(const ushort_t* __restrict__ A, const ushort_t* __restrict__ Bt,
              ushort_t* __restrict__ C)
{
    __shared__ ushort_t smem[8448];      // As[2] @ 0 / 4224; MODE0 epilogue uses [0..4224)
    const int id = blockIdx.x;
    const int tid = threadIdx.x;
    const int w = tid >> 6, lane = tid & 63;
    const int l15 = lane & 15, l4 = lane >> 4;

    int m0, z;
    if (MODE == 0) { const int b = id & 7, tl = id >> 3; m0 = (b * 32 + tl) * 64; z = b; }
    else           { z = id & 15; m0 = (id >> 4) * 64; }

    const ushort_t* Ab = A + (long)m0 * 1024;
    const ushort_t* Bb; int ldB;
    if (MODE == 0) { Bb = Bt + (long)z * 65536; ldB = 1024; }
    else           { Bb = Bt + (long)z * 1024;  ldB = 16384; }

    const int wr = (w >> 1) * 32, wc = (w & 1) * 32;
    f32x4 acc[2][2] = {};
    const int srow = lane >> 3;
    const int gchunk = (lane & 7) ^ srow;

    #pragma unroll
    for (int q = 0; q < 2; ++q) {
        const int seg = w * 2 + q;
        async16(Ab + (long)(seg * 8 + srow) * 1024 + gchunk * 8, (char*)smem + seg * 1024);
    }
    __syncthreads();

    int cur = 0;
    for (int kt = 0; kt < 1024; kt += 64) {
        if (kt + 64 < 1024) {
            const int nb = cur ^ 1;
            #pragma unroll
            for (int q = 0; q < 2; ++q) {
                const int seg = w * 2 + q;
                async16(Ab + (long)(seg * 8 + srow) * 1024 + kt + 64 + gchunk * 8,
                        (char*)smem + nb * 8448 + seg * 1024);
            }
        }
        const ushort_t* Acur = smem + cur * 4224;
        #pragma unroll
        for (int kk = 0; kk < 2; ++kk) {
            const int swz = ((kk * 4 + l4) ^ (l15 & 7)) * 8;
            bf16x8 af[2], bfr[2];
            #pragma unroll
            for (int i = 0; i < 2; ++i)
                af[i] = *(const bf16x8*)&Acur[(wr + i * 16 + l15) * 64 + swz];
            #pragma unroll
            for (int nf = 0; nf < 2; ++nf)
                bfr[nf] = *(const bf16x8*)&Bb[(long)(wc + nf * 16 + l15) * ldB + kt + kk * 32 + l4 * 8];
            __builtin_amdgcn_s_setprio(1);
            #pragma unroll
            for (int i = 0; i < 2; ++i)
                #pragma unroll
                for (int nf = 0; nf < 2; ++nf)
                    acc[i][nf] = __builtin_amdgcn_mfma_f32_16x16x32_bf16(af[i], bfr[nf], acc[i][nf], 0, 0, 0);
            __builtin_amdgcn_s_setprio(0);
        }
        __syncthreads();
        cur ^= 1;
    }

    if (MODE == 0) {
        #pragma unroll
        for (int i = 0; i < 2; ++i)
            #pragma unroll
            for (int nf = 0; nf < 2; ++nf)
                #pragma unroll
                for (int e = 0; e < 4; ++e)
                    smem[(wr + i * 16 + l4 * 4 + e) * 66 + wc + nf * 16 + l15] = f2bf(acc[i][nf][e]);
        __syncthreads();
        const int d = tid >> 2, qq = tid & 3;
        unsigned wds[8];
        #pragma unroll
        for (int u = 0; u < 8; ++u) {
            const int m = qq * 16 + u * 2;
            unsigned lo = smem[m * 66 + d];
            unsigned hi = smem[(m + 1) * 66 + d];
            wds[u] = lo | (hi << 16);
        }
        uint4 p0; unsigned* q0 = (unsigned*)&p0;
        q0[0] = wds[0]; q0[1] = wds[1]; q0[2] = wds[2]; q0[3] = wds[3];
        uint4 p1; unsigned* q1 = (unsigned*)&p1;
        q1[0] = wds[4]; q1[1] = wds[5]; q1[2] = wds[6]; q1[3] = wds[7];
        *(uint4*)&C[(long)d * 16384 + m0 + qq * 16] = p0;
        *(uint4*)&C[(long)d * 16384 + m0 + qq * 16 + 8] = p1;
    } else {
        ushort_t* Co = C + (long)z * 65536;
        #pragma unroll
        for (int i = 0; i < 2; ++i)
            #pragma unroll
            for (int nf = 0; nf < 2; ++nf)
                #pragma unroll
                for (int e = 0; e < 4; ++e)
                    Co[(long)(m0 + wr + i * 16 + l4 * 4 + e) * 64 + wc + nf * 16 + l15] = f2bf(acc[i][nf][e]);
    }
}

// ---------------- fused su + S-GEMM + softmax -> PstackT ----------------
// grid 128: b = id&7, h = id>>3.  su[s] = dot(wu[h*64+s], xsum[b]) computed in-block.
// S = W2[b][h-rows] @ wv[h-rows]^T (+ su x wvb), causal softmax, PT[b][d][h*64+s] = P[s][d]

__global__ __launch_bounds__(256)
void k_attn2(const ushort_t* __restrict__ W2, const ushort_t* __restrict__ wv,
             const ushort_t* __restrict__ wu, const float* __restrict__ xsum,
             const float* __restrict__ wvb, ushort_t* __restrict__ PT)
{
    __shared__ ushort_t PA[64 * 72];
    __shared__ float su_s[64];
    const int b = blockIdx.x & 7, h = blockIdx.x >> 3;
    const int tid = threadIdx.x;
    const int w = tid >> 6, lane = tid & 63;
    const int l15 = lane & 15, l4 = lane >> 4;

    // su for this block's 64 rows: thread group of 4 per row (rows tid>>2, same wave band)
    {
        const int rr = tid >> 2, q4 = tid & 3;
        const ushort_t* pw = wu + (long)(h * 64 + rr) * 1024 + q4 * 256;
        const float* px = xsum + b * 1024 + q4 * 256;
        float s = 0.0f;
        #pragma unroll
        for (int i = 0; i < 32; ++i) {
            bf16x8 a = *(const bf16x8*)(pw + i * 8);
            float4 f0 = *(const float4*)(px + i * 8);
            float4 f1 = *(const float4*)(px + i * 8 + 4);
            s += (float)a[0] * f0.x + (float)a[1] * f0.y + (float)a[2] * f0.z + (float)a[3] * f0.w
               + (float)a[4] * f1.x + (float)a[5] * f1.y + (float)a[6] * f1.z + (float)a[7] * f1.w;
        }
        s += __shfl_xor(s, 1, 64);
        s += __shfl_xor(s, 2, 64);
        if (q4 == 0) su_s[rr] = s;   // consumed by same wave below
    }

    f32x4 sf[4] = {};
    const ushort_t* pa  = W2 + (long)b * 1048576 + (long)(h * 64 + w * 16 + l15) * 1024 + l4 * 8;
    const ushort_t* pb0 = wv + (long)(h * 64 + l15) * 1024 + l4 * 8;

    #pragma unroll 2
    for (int kt = 0; kt < 1024; kt += 32) {
        bf16x8 a = *(const bf16x8*)(pa + kt);
        __builtin_amdgcn_s_setprio(1);
        #pragma unroll
        for (int nf = 0; nf < 4; ++nf) {
            bf16x8 bb = *(const bf16x8*)(pb0 + (long)(nf * 16) * 1024 + kt);
            sf[nf] = __builtin_amdgcn_mfma_f32_16x16x32_bf16(a, bb, sf[nf], 0, 0, 0);
        }
        __builtin_amdgcn_s_setprio(0);
    }

    const float scale = 0.03125f;   // 1/sqrt(1024)
    const int rb = w * 16 + l4 * 4;
    #pragma unroll
    for (int j = 0; j < 4; ++j) {
        const int srowi = rb + j;
        const float suv = su_s[srowi];
        float v[4];
        #pragma unroll
        for (int nf = 0; nf < 4; ++nf) {
            const int col = nf * 16 + l15;
            const float sv = sf[nf][j] + suv * wvb[h * 64 + col];
            v[nf] = (col <= srowi) ? sv * scale : -3.0e38f;
        }
        float mx = fmaxf(fmaxf(v[0], v[1]), fmaxf(v[2], v[3]));
        #pragma unroll
        for (int o = 1; o < 16; o <<= 1) mx = fmaxf(mx, __shfl_xor(mx, o, 64));
        float s = 0.0f;
        #pragma unroll
        for (int nf = 0; nf < 4; ++nf) { v[nf] = __expf(v[nf] - mx); s += v[nf]; }
        #pragma unroll
        for (int o = 1; o < 16; o <<= 1) s += __shfl_xor(s, o, 64);
        const float inv = 1.0f / s;
        #pragma unroll
        for (int nf = 0; nf < 4; ++nf)
            PA[srowi * 72 + nf * 16 + l15] = f2bf(v[nf] * inv);
    }
    __syncthreads();

    const int d = tid >> 2, qq = tid & 3;
    unsigned wds[8];
    #pragma unroll
    for (int u2 = 0; u2 < 8; ++u2) {
        unsigned lo = PA[(qq * 16 + 2 * u2) * 72 + d];
        unsigned hi = PA[(qq * 16 + 2 * u2 + 1) * 72 + d];
        wds[u2] = lo | (hi << 16);
    }
    ushort_t* dst = PT + ((long)b * 64 + d) * 1024 + h * 64 + qq * 16;
    uint4 p0; unsigned* q0 = (unsigned*)&p0;
    q0[0] = wds[0]; q0[1] = wds[1]; q0[2] = wds[2]; q0[3] = wds[3];
    uint4 p1; unsigned* q1 = (unsigned*)&p1;
    q1[0] = wds[4]; q1[1] = wds[5]; q1[2] = wds[6]; q1[3] = wds[7];
    *(uint4*)dst = p0;
    *(uint4*)(dst + 8) = p1;
}

// ---------------- launch ----------------

extern "C" void kernel_launch(void* const* d_in, const int* in_sizes, int n_in,
                              void* d_out, int out_size, void* d_ws, size_t ws_size,
                              hipStream_t stream)
{
    (void)in_sizes; (void)n_in; (void)out_size; (void)ws_size;
    const float* x   = (const float*)d_in[0];
    const float* wu  = (const float*)d_in[1];
    const float* wv  = (const float*)d_in[2];
    const float* wvb = (const float*)d_in[3];
    const float* hw  = (const float*)d_in[4];
    const float* cpw = (const float*)d_in[5];
    const float* cpb = (const float*)d_in[6];
    float* out = (float*)d_out;

    char* ws = (char*)d_ws;
    ushort_t* x_bf    = (ushort_t*)(ws);                   // 32 MB  [16384][1024]
    ushort_t* xT_bf   = (ushort_t*)(ws + 33554432L);       // 32 MB  [8][1024][2048]
    ushort_t* XtX     = (ushort_t*)(ws + 67108864L);       // 16 MB  [8][1024][1024]
    ushort_t* W2      = (ushort_t*)(ws + 83886080L);       // 16 MB  [8][1024][1024]
    ushort_t* wu_bf   = (ushort_t*)(ws + 100663296L);      // 2 MB
    ushort_t* wv_bf   = (ushort_t*)(ws + 102760448L);      // 2 MB
    ushort_t* cproj   = (ushort_t*)(ws + 104857600L);      // 2 MB
    ushort_t* helperT = (ushort_t*)(ws + 106954752L);      // 128 KB [1024][64]
    ushort_t* PT      = (ushort_t*)(ws + 107085824L);      // 1 MB   [8][64][1024]
    ushort_t* GT      = (ushort_t*)(ws + 108134400L);      // 2 MB   [64][16384]
    ushort_t* Q       = (ushort_t*)(ws + 110231552L);      // 2 MB   [16][1024][64]
    float*    xsum    = (float*)   (ws + 112328704L);      // 32 KB  [8][1024]

    // P0: merged prep (zero xsum + weight conversions + helperT)
    k_prep<<<2048, 256, 0, stream>>>(wu, wv, cpw, hw, wu_bf, wv_bf, cproj, helperT, xsum);

    // P1: x -> x_bf + xT_bf + xsum
    {
        dim3 g(32, 16, 8);
        k_trans<<<g, 256, 0, stream>>>(x, x_bf, xT_bf, xsum);
    }

    // XtX[b] = xT[b] @ xT[b]^T  (576 blocks, XCD-affine)
    k_syrk<<<576, 256, 0, stream>>>(xT_bf, XtX);

    // W2[b] = wu @ XtX[b]  (Bt = XtX by symmetry; 512 blocks, XCD-affine)
    k_gemm_bt<0, 1><<<512, 256, 0, stream>>>(wu_bf, XtX, W2, nullptr,
                                             1024, 1024, 1024, 1024, 0, 1048576L, 1048576L);

    // fused su + S + softmax -> PT
    k_attn2<<<128, 256, 0, stream>>>(W2, wv_bf, wu_bf, xsum, wvb, PT);

    // G = x @ PstackT -> GT
    k_skinny<0><<<256, 256, 0, stream>>>(x_bf, PT, GT);

    // Q[z] = cproj @ G-part
    k_skinny<1><<<256, 256, 0, stream>>>(cproj, GT, Q);

    // out[b][2c+p][o] = helperT[c][:] . Q[z][o][:] + cpb[o]
    {
        dim3 g(8, 8, 16);
        k_gemm_bt<3, 0><<<g, 256, 0, stream>>>(helperT, Q, (void*)out, cpb,
                                               64, 64, 64, 0, 0, 65536L, 0);
    }
}